// Round 12
// baseline (138.071 us; speedup 1.0000x reference)
//
#include <hip/hip_runtime.h>
#include <hip/hip_bf16.h>

#define DMODEL 1024
#define NHEAD 16
#define HDIM 64
#define CTXLEN 2048
#define BATCH 2
#define M_TOTAL (BATCH * CTXLEN)   // 4096

typedef unsigned short ushort_t;
typedef __attribute__((ext_vector_type(8))) _Float16 f16x8;
typedef __attribute__((ext_vector_type(8))) unsigned short u16x8;
typedef __attribute__((ext_vector_type(4))) float f32x4;
typedef __attribute__((ext_vector_type(4))) unsigned short u16x4;

__device__ __forceinline__ unsigned short f32_f16(float f) {
    return __builtin_bit_cast(unsigned short, (_Float16)f);
}
__device__ __forceinline__ float f16_f32(unsigned short h) {
    return (float)__builtin_bit_cast(_Float16, h);
}
__device__ __forceinline__ float fast_exp2(float x) {
    return __builtin_amdgcn_exp2f(x);
}
__device__ __forceinline__ f32x4 mfma16f(f16x8 a, f16x8 b, f32x4 c) {
    return __builtin_amdgcn_mfma_f32_16x16x32_f16(a, b, c, 0, 0, 0);
}
__device__ __forceinline__ void gload_lds16(const ushort_t* g, ushort_t* l) {
    __builtin_amdgcn_global_load_lds(
        (const __attribute__((address_space(1))) void*)g,
        (__attribute__((address_space(3))) void*)l, 16, 0, 0);
}
// QBLK=128 units: nu = (qt>>2)+1; offset of first unit of qt within a bh (40 total)
__device__ __forceinline__ int unit_off16(int qt) {
    if (qt < 4)  return qt;
    if (qt < 8)  return 4 + (qt - 4) * 2;
    if (qt < 12) return 12 + (qt - 8) * 3;
    return 24 + (qt - 12) * 4;
}

// ---------------------------------------------------------------------------
// f32 -> f16 convert (vectorized)
// ---------------------------------------------------------------------------
__global__ __launch_bounds__(256)
void conv_f32_f16(const float* __restrict__ src, ushort_t* __restrict__ dst, int n4) {
    for (int i = blockIdx.x * blockDim.x + threadIdx.x; i < n4;
         i += gridDim.x * blockDim.x) {
        const float4 v = reinterpret_cast<const float4*>(src)[i];
        u16x4 o;
        o[0] = f32_f16(v.x); o[1] = f32_f16(v.y);
        o[2] = f32_f16(v.z); o[3] = f32_f16(v.w);
        reinterpret_cast<u16x4*>(dst)[i] = o;
    }
}

// ---------------------------------------------------------------------------
// fp16 MFMA GEMM (NT): C = A·B^T. 128x128 tile, BK=32, 4 waves.
// XCD-aware bijective block swizzle (requires nwg % 8 == 0 — true for both
// launches: 768 and 256): blocks on one XCD get a contiguous logical chunk.
// ---------------------------------------------------------------------------
template<bool QKV_EPI>
__global__ __launch_bounds__(256)
void gemm_f16_nt(const ushort_t* __restrict__ A, const ushort_t* __restrict__ B,
                 const float* __restrict__ bias, float* __restrict__ C,
                 ushort_t* __restrict__ qf, ushort_t* __restrict__ kf,
                 ushort_t* __restrict__ vb,
                 int M, int N, int K) {
    __shared__ ushort_t lds[2 * 4096];

    // XCD swizzle (T1): physical dispatch ordinal -> logical tile
    int bx, by;
    {
        const int gx = gridDim.x;
        const int nwg = gx * gridDim.y;
        const int cpx = nwg >> 3;
        int flat = (int)blockIdx.y * gx + (int)blockIdx.x;
        flat = (flat & 7) * cpx + (flat >> 3);
        bx = flat % gx;
        by = flat / gx;
    }

    const int tid  = threadIdx.x;
    const int lane = tid & 63;
    const int wave = tid >> 6;
    const int lc   = lane & 15;
    const int lg   = lane >> 4;
    const int wr   = wave >> 1;
    const int wc   = wave & 1;
    const int row0 = by * 128;
    const int col0 = bx * 128;

    const int c0 = tid, c1 = 256 + tid;
    const int r0 = c0 >> 2, l0 = (c0 & 3) ^ ((c0 >> 3) & 3);
    const int r1 = c1 >> 2, l1 = (c1 & 3) ^ ((c1 >> 3) & 3);
    const size_t gaoff0 = (size_t)(row0 + r0) * K + l0 * 8;
    const size_t gaoff1 = (size_t)(row0 + r1) * K + l1 * 8;
    const size_t gboff0 = (size_t)(col0 + r0) * K + l0 * 8;
    const size_t gboff1 = (size_t)(col0 + r1) * K + l1 * 8;
    const int ld0 = c0 * 8, ld1 = c1 * 8;

    int aoff[4], boff[4];
    #pragma unroll
    for (int m = 0; m < 4; ++m) {
        const int ra = wr * 64 + m * 16 + lc;
        aoff[m] = ra * 32 + ((lg ^ ((ra >> 1) & 3)) * 8);
        const int rb = wc * 64 + m * 16 + lc;
        boff[m] = rb * 32 + ((lg ^ ((rb >> 1) & 3)) * 8);
    }

    f32x4 acc[4][4];
    const f32x4 zero4 = {0.f, 0.f, 0.f, 0.f};
    #pragma unroll
    for (int m = 0; m < 4; ++m)
        #pragma unroll
        for (int n = 0; n < 4; ++n) acc[m][n] = zero4;

    const int NT = K >> 5;

    auto stage = [&](int kt) {
        const int ko = kt * 32;
        gload_lds16(A + gaoff0 + ko, &lds[ld0]);
        gload_lds16(A + gaoff1 + ko, &lds[ld1]);
        gload_lds16(B + gboff0 + ko, &lds[4096 + ld0]);
        gload_lds16(B + gboff1 + ko, &lds[4096 + ld1]);
    };

    stage(0);
    for (int kt = 0; kt < NT; ++kt) {
        __syncthreads();
        f16x8 fa[4], fb[4];
        #pragma unroll
        for (int m = 0; m < 4; ++m) {
            fa[m] = *reinterpret_cast<const f16x8*>(&lds[aoff[m]]);
            fb[m] = *reinterpret_cast<const f16x8*>(&lds[4096 + boff[m]]);
        }
        __syncthreads();
        if (kt + 1 < NT) stage(kt + 1);
        #pragma unroll
        for (int m = 0; m < 4; ++m)
            #pragma unroll
            for (int n = 0; n < 4; ++n)
                acc[m][n] = mfma16f(fa[m], fb[n], acc[m][n]);
    }

    if (!QKV_EPI) {
        #pragma unroll
        for (int m = 0; m < 4; ++m)
            #pragma unroll
            for (int i = 0; i < 4; ++i) {
                const int r = row0 + wr * 64 + m * 16 + lg * 4 + i;
                #pragma unroll
                for (int n = 0; n < 4; ++n) {
                    const int c = col0 + wc * 64 + n * 16 + lc;
                    C[(size_t)r * N + c] = acc[m][n][i] + bias[c];
                }
            }
    } else {
        #pragma unroll
        for (int m = 0; m < 4; ++m)
            #pragma unroll
            for (int i = 0; i < 4; ++i) {
                const int r = row0 + wr * 64 + m * 16 + lg * 4 + i;
                const int bb = r >> 11;
                const int t  = r & 2047;
                #pragma unroll
                for (int n = 0; n < 4; ++n) {
                    const int cg  = col0 + wc * 64 + n * 16 + lc;
                    const int sec = cg >> 10;            // 0=q, 1=k, 2=v
                    const int ch  = cg & 1023;
                    const int hh  = ch >> 6;
                    const int d   = ch & 63;
                    const size_t off = (((size_t)(bb * NHEAD + hh)) * CTXLEN + t) * HDIM + d;
                    const unsigned short hv = f32_f16(acc[m][n][i]);
                    if (sec == 0)      qf[off] = hv;
                    else if (sec == 1) kf[off] = hv;
                    else               vb[off] = hv;
                }
            }
    }
}

// ---------------------------------------------------------------------------
// vb [bh][t][d] -> vt [bh][d][t], 64x64 tiles via LDS.
// ---------------------------------------------------------------------------
__global__ __launch_bounds__(256)
void transpose_v(const ushort_t* __restrict__ vb, ushort_t* __restrict__ vt) {
    __shared__ ushort_t T[64][66];
    const int tt = blockIdx.x;
    const int bh = blockIdx.y;
    const int tid = threadIdx.x;
    const int r  = tid >> 2;
    const int c0 = (tid & 3) * 16;

    const ushort_t* src = vb + ((size_t)bh * CTXLEN + tt * 64) * HDIM;
    #pragma unroll
    for (int half = 0; half < 2; ++half) {
        const u16x8 v = *reinterpret_cast<const u16x8*>(&src[(size_t)r * HDIM + c0 + half * 8]);
        #pragma unroll
        for (int j = 0; j < 8; ++j) T[r][c0 + half * 8 + j] = v[j];
    }
    __syncthreads();
    ushort_t* dst = vt + ((size_t)bh * HDIM + r) * CTXLEN + tt * 64 + c0;
    u16x8 o0, o1;
    #pragma unroll
    for (int j = 0; j < 8; ++j) { o0[j] = T[c0 + j][r]; o1[j] = T[c0 + 8 + j][r]; }
    *reinterpret_cast<u16x8*>(&dst[0]) = o0;
    *reinterpret_cast<u16x8*>(&dst[8]) = o1;
}

// ---------------------------------------------------------------------------
// Flash causal attention v8: split-KV + QBLK=128 (wave owns 32 q-rows via
// m-loop; K/V frags read once per step, reused for both m-halves -> LDS
// reads, barriers, staging per q-row all halved vs v7).
// Grid 1280 = 40 units x 32 bh (id = u_off*32 + bh; id%8=bh%8 keeps same-bh
// blocks on one XCD for K/V L2 locality). Unit covers <=8 K-tile steps,
// writes unnormalized y (f16) + m,l (f32).
// ---------------------------------------------------------------------------
#define SCALE_LOG2 11.5415603271f   // 8 * log2(e)

__global__ __launch_bounds__(256)
void attn_fwd8(const ushort_t* __restrict__ qf, const ushort_t* __restrict__ kf,
               const ushort_t* __restrict__ vt,
               ushort_t* __restrict__ py, float* __restrict__ pml) {
    __shared__ ushort_t KH[2][4096];
    __shared__ ushort_t VT[2][4096];
    __shared__ ushort_t Ps[4][16][64];

    const int id    = blockIdx.x;
    const int bh    = id & 31;
    const int u_off = id >> 5;                 // 0..39
    int qt, u;
    if (u_off < 4)       { qt = u_off;                                   u = 0; }
    else if (u_off < 12) { const int t = u_off - 4;  qt = 4  + (t >> 1); u = t & 1; }
    else if (u_off < 24) { const int t = u_off - 12; const int q3 = t / 3; qt = 8 + q3; u = t - q3 * 3; }
    else                 { const int t = u_off - 24; qt = 12 + (t >> 2); u = t & 3; }
    const int total = 2 * qt + 2;              // k-tiles for this 128-row q block
    const int nu    = (qt >> 2) + 1;
    const int base  = total / nu, rem = total % nu;
    const int kb0   = u * base + (u < rem ? u : rem);
    const int len   = base + (u < rem ? 1 : 0);
    const int slot  = bh * 40 + u_off;

    const int tid  = threadIdx.x;
    const int wave = tid >> 6;
    const int lane = tid & 63;
    const int lc   = lane & 15;
    const int lg   = lane >> 4;

    const ushort_t* kfb = kf + (size_t)bh * CTXLEN * HDIM;
    const ushort_t* vtb = vt + (size_t)bh * HDIM * CTXLEN;

    const int cA = tid, cB = 256 + tid;
    const int rA = cA >> 3, sgA = (cA & 7) ^ (rA & 7);
    const int rB = cB >> 3, sgB = (cB & 7) ^ (rB & 7);

    auto stage = [&](int kb, int buf) {
        const size_t koff = (size_t)(kb * 64);
        gload_lds16(kfb + (koff + rA) * HDIM + sgA * 8, &KH[buf][cA * 8]);
        gload_lds16(kfb + (koff + rB) * HDIM + sgB * 8, &KH[buf][cB * 8]);
        gload_lds16(vtb + (size_t)rA * CTXLEN + kb * 64 + sgA * 8, &VT[buf][cA * 8]);
        gload_lds16(vtb + (size_t)rB * CTXLEN + kb * 64 + sgB * 8, &VT[buf][cB * 8]);
    };

    // Q fragments: wave owns rows qt*128 + wave*32 + m*16 + lc, m in {0,1}
    const size_t qrow0 = (size_t)bh * CTXLEN + qt * 128 + wave * 32;
    f16x8 qfr[2][2];   // [m][ds]
    #pragma unroll
    for (int m = 0; m < 2; ++m)
        #pragma unroll
        for (int ds = 0; ds < 2; ++ds)
            qfr[m][ds] = *reinterpret_cast<const f16x8*>(
                &qf[(qrow0 + m * 16 + lc) * HDIM + ds * 32 + lg * 8]);

    const f32x4 zero4 = {0.f, 0.f, 0.f, 0.f};
    f32x4 yacc[2][4];   // [m][t]: y^T, d = t*16+lg*4+i, q = lc
    #pragma unroll
    for (int m = 0; m < 2; ++m)
        #pragma unroll
        for (int t = 0; t < 4; ++t) yacc[m][t] = zero4;
    float m_i[2] = {-1e30f, -1e30f};
    float l_i[2] = {0.f, 0.f};

    stage(kb0, 0);
    __syncthreads();

    int cur = 0;
    for (int s = 0; s < len; ++s) {
        const int kb = kb0 + s;
        if (s + 1 < len) stage(kb + 1, cur ^ 1);

        // K fragments (swizzled) — shared across both m-halves
        f16x8 kfr[4][2];
        #pragma unroll
        for (int tc = 0; tc < 4; ++tc) {
            const int rk = tc * 16 + lc;
            #pragma unroll
            for (int ds = 0; ds < 2; ++ds) {
                const int a = rk * 64 + (((ds * 4 + lg) ^ (rk & 7)) * 8);
                kfr[tc][ds] = *reinterpret_cast<const f16x8*>(&KH[cur][a]);
            }
        }
        // V^T fragments (swizzled) — shared across both m-halves
        f16x8 vf[4][2];
        #pragma unroll
        for (int t = 0; t < 4; ++t) {
            const int rv = t * 16 + lc;
            #pragma unroll
            for (int ks = 0; ks < 2; ++ks) {
                const int a = rv * 64 + (((ks * 4 + lg) ^ (rv & 7)) * 8);
                vf[t][ks] = *reinterpret_cast<const f16x8*>(&VT[cur][a]);
            }
        }

        // S^T = K Q^T for both m-halves
        f32x4 sacc[2][4];
        #pragma unroll
        for (int m = 0; m < 2; ++m)
            #pragma unroll
            for (int tc = 0; tc < 4; ++tc) sacc[m][tc] = zero4;
        __builtin_amdgcn_s_setprio(1);
        #pragma unroll
        for (int m = 0; m < 2; ++m)
            #pragma unroll
            for (int tc = 0; tc < 4; ++tc)
                #pragma unroll
                for (int ds = 0; ds < 2; ++ds)
                    sacc[m][tc] = mfma16f(kfr[tc][ds], qfr[m][ds], sacc[m][tc]);
        __builtin_amdgcn_s_setprio(0);

        const int dko = (kb - 2 * qt) * 64;   // >=0 only on the two diag tiles

        #pragma unroll
        for (int m = 0; m < 2; ++m) {
            const int q_loc = wave * 32 + m * 16 + lc;
            float p[4][4];
            #pragma unroll
            for (int tc = 0; tc < 4; ++tc)
                #pragma unroll
                for (int i = 0; i < 4; ++i) {
                    float uu = sacc[m][tc][i] * SCALE_LOG2;
                    if (dko >= 0 && (dko + tc * 16 + lg * 4 + i) > q_loc) uu = -1e30f;
                    p[tc][i] = uu;
                }
            float mx = p[0][0];
            #pragma unroll
            for (int tc = 0; tc < 4; ++tc)
                #pragma unroll
                for (int i = 0; i < 4; ++i) mx = fmaxf(mx, p[tc][i]);
            mx = fmaxf(mx, __shfl_xor(mx, 16));
            mx = fmaxf(mx, __shfl_xor(mx, 32));
            const float mnew = fmaxf(m_i[m], mx);
            const float corr = fast_exp2(m_i[m] - mnew);
            float psum = 0.f;
            #pragma unroll
            for (int tc = 0; tc < 4; ++tc)
                #pragma unroll
                for (int i = 0; i < 4; ++i) {
                    const float e = fast_exp2(p[tc][i] - mnew);
                    p[tc][i] = e;
                    psum += e;
                }
            psum += __shfl_xor(psum, 16);
            psum += __shfl_xor(psum, 32);
            l_i[m] = l_i[m] * corr + psum;
            m_i[m] = mnew;
            #pragma unroll
            for (int t = 0; t < 4; ++t) yacc[m][t] *= corr;

            // P -> Ps (wave-private, swizzled; reused sequentially across m)
            #pragma unroll
            for (int tc = 0; tc < 4; ++tc) {
                const int eb = tc * 16 + lg * 4;
                const int se = ((((eb >> 3) ^ (lc & 7)) << 3) | (eb & 7));
                u16x4 pk;
                #pragma unroll
                for (int i = 0; i < 4; ++i) pk[i] = f32_f16(p[tc][i]);
                *reinterpret_cast<u16x4*>(&Ps[wave][lc][se]) = pk;
            }
            f16x8 pa[2];
            #pragma unroll
            for (int ks = 0; ks < 2; ++ks) {
                const int sl = ((ks * 4 + lg) ^ (lc & 7)) << 3;
                pa[ks] = *reinterpret_cast<const f16x8*>(&Ps[wave][lc][sl]);
            }
            __builtin_amdgcn_s_setprio(1);
            #pragma unroll
            for (int t = 0; t < 4; ++t)
                #pragma unroll
                for (int ks = 0; ks < 2; ++ks)
                    yacc[m][t] = mfma16f(vf[t][ks], pa[ks], yacc[m][t]);
            __builtin_amdgcn_s_setprio(0);
        }

        __syncthreads();
        cur ^= 1;
    }

    // partial epilogue: unnormalized y (f16) + m,l (f32)
    #pragma unroll
    for (int m = 0; m < 2; ++m) {
        const int row = wave * 32 + m * 16 + lc;
        ushort_t* prow = py + ((size_t)slot * 128 + row) * 64;
        #pragma unroll
        for (int t = 0; t < 4; ++t) {
            u16x4 o;
            #pragma unroll
            for (int i = 0; i < 4; ++i) o[i] = f32_f16(yacc[m][t][i]);
            *reinterpret_cast<u16x4*>(&prow[t * 16 + lg * 4]) = o;
        }
        if (lg == 0) {
            pml[(size_t)slot * 256 + row]       = m_i[m];
            pml[(size_t)slot * 256 + 128 + row] = l_i[m];
        }
    }
}

// ---------------------------------------------------------------------------
// Merge split-KV partials: per (bh, qt) combine nu units -> yb f16.
// Grid 512 = bh*16+qt, 256 threads: row = tid/2 (0..127), d-half = (tid&1)*32.
// ---------------------------------------------------------------------------
__global__ __launch_bounds__(256)
void merge_attn8(const ushort_t* __restrict__ py, const float* __restrict__ pml,
                 ushort_t* __restrict__ yb) {
    const int bid = blockIdx.x;
    const int bh  = bid >> 4;
    const int qt  = bid & 15;
    const int b   = bh >> 4;
    const int h   = bh & 15;
    const int tid = threadIdx.x;
    const int row = tid >> 1;
    const int d0  = (tid & 1) * 32;

    const int nu    = (qt >> 2) + 1;
    const int sbase = bh * 40 + unit_off16(qt);

    float mu[4], lu[4];
    float M = -1e30f;
    #pragma unroll
    for (int u = 0; u < 4; ++u) {
        if (u < nu) {
            mu[u] = pml[(size_t)(sbase + u) * 256 + row];
            lu[u] = pml[(size_t)(sbase + u) * 256 + 128 + row];
            M = fmaxf(M, mu[u]);
        } else { mu[u] = -1e30f; lu[u] = 0.f; }
    }
    float w[4], ltot = 0.f;
    #pragma unroll
    for (int u = 0; u < 4; ++u) {
        w[u] = (u < nu) ? fast_exp2(mu[u] - M) : 0.f;
        ltot += w[u] * lu[u];
    }

    float y[32];
    #pragma unroll
    for (int j = 0; j < 32; ++j) y[j] = 0.f;
    #pragma unroll
    for (int u = 0; u < 4; ++u) {
        if (u < nu) {
            const ushort_t* pr = py + ((size_t)(sbase + u) * 128 + row) * 64 + d0;
            #pragma unroll
            for (int c = 0; c < 4; ++c) {
                const u16x8 a = *reinterpret_cast<const u16x8*>(&pr[c * 8]);
                #pragma unroll
                for (int j = 0; j < 8; ++j) y[c * 8 + j] += w[u] * f16_f32(a[j]);
            }
        }
    }
    const float inv = 1.0f / ltot;
    ushort_t* dst = yb + (size_t)(b * CTXLEN + qt * 128 + row) * DMODEL + h * HDIM + d0;
    #pragma unroll
    for (int c = 0; c < 4; ++c) {
        u16x8 o;
        #pragma unroll
        for (int j = 0; j < 8; ++j) o[j] = f32_f16(y[c * 8 + j] * inv);
        *reinterpret_cast<u16x8*>(&dst[c * 8]) = o;
    }
}

// ---------------------------------------------------------------------------
extern "C" void kernel_launch(void* const* d_in, const int* in_sizes, int n_in,
                              void* d_out, int out_size, void* d_ws, size_t ws_size,
                              hipStream_t stream) {
    const float* x      = (const float*)d_in[0];
    const float* w_qkv  = (const float*)d_in[1];
    const float* w_proj = (const float*)d_in[2];
    const float* b_proj = (const float*)d_in[3];
    float* out = (float*)d_out;

    // ws layout (bytes):
    //   wqf f16 [3072,1024]                 @ 0          (6,291,456)
    //   wpf f16 [1024,1024]                 @ 6291456    (2,097,152)
    //   xf  f16 [4096,1024] | yb f16 reuse  @ 8388608    (8,388,608)
    //   qf  f16 [32][2048][64]              @ 16777216   (8,388,608)
    //   kf  f16 [32][2048][64]              @ 25165824   (8,388,608)
    //   vb  f16 [32][2048][64]              @ 33554432   (8,388,608)
    //   vt  f16 [32][64][2048]              @ 41943040   (8,388,608)
    //   py  f16 [1280][128][64]             @ 50331648   (20,971,520)
    //   pml f32 [1280][256]                 @ 71303168   ( 1,310,720)
    char* ws = (char*)d_ws;
    ushort_t* wqf = (ushort_t*)(ws);
    ushort_t* wpf = (ushort_t*)(ws + 6291456);
    ushort_t* xf  = (ushort_t*)(ws + 8388608);
    ushort_t* qf  = (ushort_t*)(ws + 16777216);
    ushort_t* kf  = (ushort_t*)(ws + 25165824);
    ushort_t* vb  = (ushort_t*)(ws + 33554432);
    ushort_t* vt  = (ushort_t*)(ws + 41943040);
    ushort_t* py  = (ushort_t*)(ws + 50331648);
    float*    pml = (float*)   (ws + 71303168);
    ushort_t* yb  = xf;   // reused after qkv GEMM consumed xf

    const dim3 blk(256);

    conv_f32_f16<<<dim3(2048), blk, 0, stream>>>(x, xf, M_TOTAL * DMODEL / 4);
    conv_f32_f16<<<dim3(2048), blk, 0, stream>>>(w_qkv, wqf, 3 * DMODEL * DMODEL / 4);
    conv_f32_f16<<<dim3(1024), blk, 0, stream>>>(w_proj, wpf, DMODEL * DMODEL / 4);

    // qkv = x @ w_qkv^T, single fp16 GEMM (N=3072), epilogue scatters q/k/v
    gemm_f16_nt<true><<<dim3(3 * DMODEL / 128, M_TOTAL / 128), blk, 0, stream>>>(
        xf, wqf, nullptr, nullptr, qf, kf, vb, M_TOTAL, 3 * DMODEL, DMODEL);

    transpose_v<<<dim3(CTXLEN / 64, BATCH * NHEAD), blk, 0, stream>>>(vb, vt);

    // split-KV attention units (QBLK=128) + merge
    attn_fwd8<<<dim3(1280), blk, 0, stream>>>(qf, kf, vt, py, pml);
    merge_attn8<<<dim3(512), blk, 0, stream>>>(py, pml, yb);

    // out = y @ w_proj^T + b
    gemm_f16_nt<false><<<dim3(DMODEL / 128, M_TOTAL / 128), blk, 0, stream>>>(
        yb, wpf, b_proj, out, nullptr, nullptr, nullptr, M_TOTAL, DMODEL, DMODEL);
}

// Round 13
// 133.499 us; speedup vs baseline: 1.0342x; 1.0342x over previous
//
#include <hip/hip_runtime.h>
#include <hip/hip_bf16.h>

#define DMODEL 1024
#define NHEAD 16
#define HDIM 64
#define CTXLEN 2048
#define BATCH 2
#define M_TOTAL (BATCH * CTXLEN)   // 4096

typedef unsigned short ushort_t;
typedef __attribute__((ext_vector_type(8))) _Float16 f16x8;
typedef __attribute__((ext_vector_type(8))) unsigned short u16x8;
typedef __attribute__((ext_vector_type(4))) float f32x4;
typedef __attribute__((ext_vector_type(4))) unsigned short u16x4;

__device__ __forceinline__ unsigned short f32_f16(float f) {
    return __builtin_bit_cast(unsigned short, (_Float16)f);
}
__device__ __forceinline__ float f16_f32(unsigned short h) {
    return (float)__builtin_bit_cast(_Float16, h);
}
__device__ __forceinline__ float fast_exp2(float x) {
    return __builtin_amdgcn_exp2f(x);
}
__device__ __forceinline__ f32x4 mfma16f(f16x8 a, f16x8 b, f32x4 c) {
    return __builtin_amdgcn_mfma_f32_16x16x32_f16(a, b, c, 0, 0, 0);
}
__device__ __forceinline__ void gload_lds16(const ushort_t* g, ushort_t* l) {
    __builtin_amdgcn_global_load_lds(
        (const __attribute__((address_space(1))) void*)g,
        (__attribute__((address_space(3))) void*)l, 16, 0, 0);
}
// units per q-tile: nu = qt/8+1; slot offset of first unit of qt within a bh
__device__ __forceinline__ int unit_off(int qt) {
    if (qt < 8)  return qt;
    if (qt < 16) return 8 + (qt - 8) * 2;
    if (qt < 24) return 24 + (qt - 16) * 3;
    return 48 + (qt - 24) * 4;
}

// ---------------------------------------------------------------------------
// fused f32 -> f16 convert for 3 arrays (one launch)
// ---------------------------------------------------------------------------
__global__ __launch_bounds__(256)
void conv3_f32_f16(const float* __restrict__ a, ushort_t* __restrict__ da, int na4,
                   const float* __restrict__ b, ushort_t* __restrict__ db, int nb4,
                   const float* __restrict__ c, ushort_t* __restrict__ dc, int nc4) {
    const int n = na4 + nb4 + nc4;
    for (int i = blockIdx.x * blockDim.x + threadIdx.x; i < n;
         i += gridDim.x * blockDim.x) {
        const float* s; ushort_t* d; int j = i;
        if (j < na4) { s = a; d = da; }
        else if (j - na4 < nb4) { j -= na4; s = b; d = db; }
        else { j -= na4 + nb4; s = c; d = dc; }
        const float4 v = reinterpret_cast<const float4*>(s)[j];
        u16x4 o;
        o[0] = f32_f16(v.x); o[1] = f32_f16(v.y);
        o[2] = f32_f16(v.z); o[3] = f32_f16(v.w);
        reinterpret_cast<u16x4*>(d)[j] = o;
    }
}

// ---------------------------------------------------------------------------
// fp16 MFMA GEMM (NT): C = A·B^T. 128x128 tile, BK=32, 4 waves. (R10 verbatim)
// ---------------------------------------------------------------------------
template<bool QKV_EPI>
__global__ __launch_bounds__(256)
void gemm_f16_nt(const ushort_t* __restrict__ A, const ushort_t* __restrict__ B,
                 const float* __restrict__ bias, float* __restrict__ C,
                 ushort_t* __restrict__ qf, ushort_t* __restrict__ kf,
                 ushort_t* __restrict__ vb,
                 int M, int N, int K) {
    __shared__ ushort_t lds[2 * 4096];

    const int tid  = threadIdx.x;
    const int lane = tid & 63;
    const int wave = tid >> 6;
    const int lc   = lane & 15;
    const int lg   = lane >> 4;
    const int wr   = wave >> 1;
    const int wc   = wave & 1;
    const int row0 = blockIdx.y * 128;
    const int col0 = blockIdx.x * 128;

    const int c0 = tid, c1 = 256 + tid;
    const int r0 = c0 >> 2, l0 = (c0 & 3) ^ ((c0 >> 3) & 3);
    const int r1 = c1 >> 2, l1 = (c1 & 3) ^ ((c1 >> 3) & 3);
    const size_t gaoff0 = (size_t)(row0 + r0) * K + l0 * 8;
    const size_t gaoff1 = (size_t)(row0 + r1) * K + l1 * 8;
    const size_t gboff0 = (size_t)(col0 + r0) * K + l0 * 8;
    const size_t gboff1 = (size_t)(col0 + r1) * K + l1 * 8;
    const int ld0 = c0 * 8, ld1 = c1 * 8;

    int aoff[4], boff[4];
    #pragma unroll
    for (int m = 0; m < 4; ++m) {
        const int ra = wr * 64 + m * 16 + lc;
        aoff[m] = ra * 32 + ((lg ^ ((ra >> 1) & 3)) * 8);
        const int rb = wc * 64 + m * 16 + lc;
        boff[m] = rb * 32 + ((lg ^ ((rb >> 1) & 3)) * 8);
    }

    f32x4 acc[4][4];
    const f32x4 zero4 = {0.f, 0.f, 0.f, 0.f};
    #pragma unroll
    for (int m = 0; m < 4; ++m)
        #pragma unroll
        for (int n = 0; n < 4; ++n) acc[m][n] = zero4;

    const int NT = K >> 5;

    auto stage = [&](int kt) {
        const int ko = kt * 32;
        gload_lds16(A + gaoff0 + ko, &lds[ld0]);
        gload_lds16(A + gaoff1 + ko, &lds[ld1]);
        gload_lds16(B + gboff0 + ko, &lds[4096 + ld0]);
        gload_lds16(B + gboff1 + ko, &lds[4096 + ld1]);
    };

    stage(0);
    for (int kt = 0; kt < NT; ++kt) {
        __syncthreads();
        f16x8 fa[4], fb[4];
        #pragma unroll
        for (int m = 0; m < 4; ++m) {
            fa[m] = *reinterpret_cast<const f16x8*>(&lds[aoff[m]]);
            fb[m] = *reinterpret_cast<const f16x8*>(&lds[4096 + boff[m]]);
        }
        __syncthreads();
        if (kt + 1 < NT) stage(kt + 1);
        #pragma unroll
        for (int m = 0; m < 4; ++m)
            #pragma unroll
            for (int n = 0; n < 4; ++n)
                acc[m][n] = mfma16f(fa[m], fb[n], acc[m][n]);
    }

    if (!QKV_EPI) {
        #pragma unroll
        for (int m = 0; m < 4; ++m)
            #pragma unroll
            for (int i = 0; i < 4; ++i) {
                const int r = row0 + wr * 64 + m * 16 + lg * 4 + i;
                #pragma unroll
                for (int n = 0; n < 4; ++n) {
                    const int c = col0 + wc * 64 + n * 16 + lc;
                    C[(size_t)r * N + c] = acc[m][n][i] + bias[c];
                }
            }
    } else {
        #pragma unroll
        for (int m = 0; m < 4; ++m)
            #pragma unroll
            for (int i = 0; i < 4; ++i) {
                const int r = row0 + wr * 64 + m * 16 + lg * 4 + i;
                const int bb = r >> 11;
                const int t  = r & 2047;
                #pragma unroll
                for (int n = 0; n < 4; ++n) {
                    const int cg  = col0 + wc * 64 + n * 16 + lc;
                    const int sec = cg >> 10;            // 0=q, 1=k, 2=v
                    const int ch  = cg & 1023;
                    const int hh  = ch >> 6;
                    const int d   = ch & 63;
                    const size_t off = (((size_t)(bb * NHEAD + hh)) * CTXLEN + t) * HDIM + d;
                    const unsigned short hv = f32_f16(acc[m][n][i]);
                    if (sec == 0)      qf[off] = hv;
                    else if (sec == 1) kf[off] = hv;
                    else               vb[off] = hv;
                }
            }
    }
}

// ---------------------------------------------------------------------------
// vb [bh][t][d] -> vt [bh][d][t], 64x64 tiles via LDS. (R10 verbatim)
// ---------------------------------------------------------------------------
__global__ __launch_bounds__(256)
void transpose_v(const ushort_t* __restrict__ vb, ushort_t* __restrict__ vt) {
    __shared__ ushort_t T[64][66];
    const int tt = blockIdx.x;
    const int bh = blockIdx.y;
    const int tid = threadIdx.x;
    const int r  = tid >> 2;
    const int c0 = (tid & 3) * 16;

    const ushort_t* src = vb + ((size_t)bh * CTXLEN + tt * 64) * HDIM;
    #pragma unroll
    for (int half = 0; half < 2; ++half) {
        const u16x8 v = *reinterpret_cast<const u16x8*>(&src[(size_t)r * HDIM + c0 + half * 8]);
        #pragma unroll
        for (int j = 0; j < 8; ++j) T[r][c0 + half * 8 + j] = v[j];
    }
    __syncthreads();
    ushort_t* dst = vt + ((size_t)bh * HDIM + r) * CTXLEN + tt * 64 + c0;
    u16x8 o0, o1;
    #pragma unroll
    for (int j = 0; j < 8; ++j) { o0[j] = T[c0 + j][r]; o1[j] = T[c0 + 8 + j][r]; }
    *reinterpret_cast<u16x8*>(&dst[0]) = o0;
    *reinterpret_cast<u16x8*>(&dst[8]) = o1;
}

// ---------------------------------------------------------------------------
// Flash causal attention v9: R10's split-KV (QBLK=64, units <=8 steps)
// + cross-step software pipeline: at step s, QK(s) MFMAs issue first, then
// softmax(s-1)+PV(s-1) run from registers (sacc_c, vfp carried across the
// barrier) -> QK executes on the MFMA pipe under softmax's VALU chain.
// + defer-max (T13, THR=8): skip corr/rescale when max didn't grow.
// Grid 2560 = 80 units x 32 bh.
// ---------------------------------------------------------------------------
#define SCALE_LOG2 11.5415603271f   // 8 * log2(e)

__global__ __launch_bounds__(256)
void attn_fwd9(const ushort_t* __restrict__ qf, const ushort_t* __restrict__ kf,
               const ushort_t* __restrict__ vt,
               ushort_t* __restrict__ py, float* __restrict__ pml) {
    __shared__ ushort_t KH[2][4096];
    __shared__ ushort_t VT[2][4096];
    __shared__ ushort_t Ps[4][16][64];

    const int id    = blockIdx.x;
    const int bh    = id & 31;
    const int u_off = id >> 5;                 // 0..79
    int qt, u;
    if (u_off < 8)       { qt = u_off;                          u = 0; }
    else if (u_off < 24) { const int t = u_off - 8;  qt = 8  + (t >> 1); u = t & 1; }
    else if (u_off < 48) { const int t = u_off - 24; const int q3 = t / 3; qt = 16 + q3; u = t - q3 * 3; }
    else                 { const int t = u_off - 48; qt = 24 + (t >> 2); u = t & 3; }
    const int total = qt + 1;
    const int nu    = (qt >> 3) + 1;
    const int base  = total / nu, rem = total % nu;
    const int kb0   = u * base + (u < rem ? u : rem);
    const int len   = base + (u < rem ? 1 : 0);
    const int slot  = bh * 80 + u_off;

    const int tid  = threadIdx.x;
    const int wave = tid >> 6;
    const int lane = tid & 63;
    const int lc   = lane & 15;
    const int lg   = lane >> 4;

    const ushort_t* kfb = kf + (size_t)bh * CTXLEN * HDIM;
    const ushort_t* vtb = vt + (size_t)bh * HDIM * CTXLEN;

    const int cA = tid, cB = 256 + tid;
    const int rA = cA >> 3, sgA = (cA & 7) ^ (rA & 7);
    const int rB = cB >> 3, sgB = (cB & 7) ^ (rB & 7);

    auto stage = [&](int kb, int buf) {
        const size_t koff = (size_t)(kb * 64);
        gload_lds16(kfb + (koff + rA) * HDIM + sgA * 8, &KH[buf][cA * 8]);
        gload_lds16(kfb + (koff + rB) * HDIM + sgB * 8, &KH[buf][cB * 8]);
        gload_lds16(vtb + (size_t)rA * CTXLEN + kb * 64 + sgA * 8, &VT[buf][cA * 8]);
        gload_lds16(vtb + (size_t)rB * CTXLEN + kb * 64 + sgB * 8, &VT[buf][cB * 8]);
    };

    // Q fragments: q row = qt*64 + wave*16 + lc
    const size_t qrow = (size_t)bh * CTXLEN + qt * 64 + wave * 16 + lc;
    f16x8 qfr[2];
    #pragma unroll
    for (int ds = 0; ds < 2; ++ds)
        qfr[ds] = *reinterpret_cast<const f16x8*>(&qf[qrow * HDIM + ds * 32 + lg * 8]);

    const f32x4 zero4 = {0.f, 0.f, 0.f, 0.f};
    f32x4 yacc[4];
    #pragma unroll
    for (int t = 0; t < 4; ++t) yacc[t] = zero4;
    float m_i = -1e30f, l_i = 0.f;

    // deferred-phase state (carried across the barrier)
    f32x4 sacc_c[4];
    f16x8 vfp[4][2];

    // softmax(sacc_c for tile kb_c) + PV with vfp  — updates yacc/m_i/l_i
    auto softmax_pv = [&](int kb_c) {
        const bool diag = (kb_c == qt);
        const int q_loc = wave * 16 + lc;
        float p[4][4];
        #pragma unroll
        for (int tc = 0; tc < 4; ++tc)
            #pragma unroll
            for (int i = 0; i < 4; ++i) {
                float uu = sacc_c[tc][i] * SCALE_LOG2;
                if (diag && (tc * 16 + lg * 4 + i) > q_loc) uu = -1e30f;
                p[tc][i] = uu;
            }
        float mx = p[0][0];
        #pragma unroll
        for (int tc = 0; tc < 4; ++tc)
            #pragma unroll
            for (int i = 0; i < 4; ++i) mx = fmaxf(mx, p[tc][i]);
        mx = fmaxf(mx, __shfl_xor(mx, 16));
        mx = fmaxf(mx, __shfl_xor(mx, 32));
        if (__all(mx <= m_i + 8.0f)) {
            // defer-max: keep m_i, no rescale (p bounded by 2^8, f16-safe)
            float psum = 0.f;
            #pragma unroll
            for (int tc = 0; tc < 4; ++tc)
                #pragma unroll
                for (int i = 0; i < 4; ++i) {
                    const float e = fast_exp2(p[tc][i] - m_i);
                    p[tc][i] = e;
                    psum += e;
                }
            psum += __shfl_xor(psum, 16);
            psum += __shfl_xor(psum, 32);
            l_i += psum;
        } else {
            const float mnew = fmaxf(m_i, mx);
            const float corr = fast_exp2(m_i - mnew);
            float psum = 0.f;
            #pragma unroll
            for (int tc = 0; tc < 4; ++tc)
                #pragma unroll
                for (int i = 0; i < 4; ++i) {
                    const float e = fast_exp2(p[tc][i] - mnew);
                    p[tc][i] = e;
                    psum += e;
                }
            psum += __shfl_xor(psum, 16);
            psum += __shfl_xor(psum, 32);
            l_i = l_i * corr + psum;
            m_i = mnew;
            #pragma unroll
            for (int t = 0; t < 4; ++t) yacc[t] *= corr;
        }
        // P -> Ps (wave-private, swizzled)
        #pragma unroll
        for (int tc = 0; tc < 4; ++tc) {
            const int eb = tc * 16 + lg * 4;
            const int se = ((((eb >> 3) ^ (lc & 7)) << 3) | (eb & 7));
            u16x4 pk;
            #pragma unroll
            for (int i = 0; i < 4; ++i) pk[i] = f32_f16(p[tc][i]);
            *reinterpret_cast<u16x4*>(&Ps[wave][lc][se]) = pk;
        }
        f16x8 pa[2];
        #pragma unroll
        for (int ks = 0; ks < 2; ++ks) {
            const int sl = ((ks * 4 + lg) ^ (lc & 7)) << 3;
            pa[ks] = *reinterpret_cast<const f16x8*>(&Ps[wave][lc][sl]);
        }
        __builtin_amdgcn_s_setprio(1);
        #pragma unroll
        for (int t = 0; t < 4; ++t)
            #pragma unroll
            for (int ks = 0; ks < 2; ++ks)
                yacc[t] = mfma16f(vfp[t][ks], pa[ks], yacc[t]);
        __builtin_amdgcn_s_setprio(0);
    };

    stage(kb0, 0);
    __syncthreads();                 // buf0 staged
    if (len > 1) stage(kb0 + 1, 1);  // buf1 untouched by readers yet: safe

    // prologue: QK(0) -> sacc_c; vfp = V(0)
    {
        f16x8 kfr[4][2];
        #pragma unroll
        for (int tc = 0; tc < 4; ++tc) {
            const int rk = tc * 16 + lc;
            #pragma unroll
            for (int ds = 0; ds < 2; ++ds) {
                const int a = rk * 64 + (((ds * 4 + lg) ^ (rk & 7)) * 8);
                kfr[tc][ds] = *reinterpret_cast<const f16x8*>(&KH[0][a]);
            }
        }
        #pragma unroll
        for (int tc = 0; tc < 4; ++tc) sacc_c[tc] = zero4;
        __builtin_amdgcn_s_setprio(1);
        #pragma unroll
        for (int tc = 0; tc < 4; ++tc)
            #pragma unroll
            for (int ds = 0; ds < 2; ++ds)
                sacc_c[tc] = mfma16f(kfr[tc][ds], qfr[ds], sacc_c[tc]);
        __builtin_amdgcn_s_setprio(0);
        #pragma unroll
        for (int t = 0; t < 4; ++t) {
            const int rv = t * 16 + lc;
            #pragma unroll
            for (int ks = 0; ks < 2; ++ks) {
                const int a = rv * 64 + (((ks * 4 + lg) ^ (rv & 7)) * 8);
                vfp[t][ks] = *reinterpret_cast<const f16x8*>(&VT[0][a]);
            }
        }
    }

    for (int s = 1; s < len; ++s) {
        __syncthreads();             // buf(s) staged; all reads of buf(s-1) done
        if (s + 1 < len) stage(kb0 + s + 1, (s + 1) & 1);   // overwrites buf(s-1)
        const int bufs = s & 1;

        // QK(s) -> sacc_n (MFMA pipe; runs under the deferred softmax below)
        f32x4 sacc_n[4];
        {
            f16x8 kfr[4][2];
            #pragma unroll
            for (int tc = 0; tc < 4; ++tc) {
                const int rk = tc * 16 + lc;
                #pragma unroll
                for (int ds = 0; ds < 2; ++ds) {
                    const int a = rk * 64 + (((ds * 4 + lg) ^ (rk & 7)) * 8);
                    kfr[tc][ds] = *reinterpret_cast<const f16x8*>(&KH[bufs][a]);
                }
            }
            #pragma unroll
            for (int tc = 0; tc < 4; ++tc) sacc_n[tc] = zero4;
            __builtin_amdgcn_s_setprio(1);
            #pragma unroll
            for (int tc = 0; tc < 4; ++tc)
                #pragma unroll
                for (int ds = 0; ds < 2; ++ds)
                    sacc_n[tc] = mfma16f(kfr[tc][ds], qfr[ds], sacc_n[tc]);
            __builtin_amdgcn_s_setprio(0);
        }

        // deferred softmax + PV for tile s-1 (registers only)
        softmax_pv(kb0 + s - 1);

        // load V(s) for next deferral (buf s not staged-over this step)
        #pragma unroll
        for (int t = 0; t < 4; ++t) {
            const int rv = t * 16 + lc;
            #pragma unroll
            for (int ks = 0; ks < 2; ++ks) {
                const int a = rv * 64 + (((ks * 4 + lg) ^ (rv & 7)) * 8);
                vfp[t][ks] = *reinterpret_cast<const f16x8*>(&VT[bufs][a]);
            }
        }
        #pragma unroll
        for (int tc = 0; tc < 4; ++tc) sacc_c[tc] = sacc_n[tc];
    }

    // final deferred tile
    softmax_pv(kb0 + len - 1);

    // partial epilogue: unnormalized y (f16) + m,l (f32)
    const int row = wave * 16 + lc;
    ushort_t* prow = py + ((size_t)slot * 64 + row) * 64;
    #pragma unroll
    for (int t = 0; t < 4; ++t) {
        u16x4 o;
        #pragma unroll
        for (int i = 0; i < 4; ++i) o[i] = f32_f16(yacc[t][i]);
        *reinterpret_cast<u16x4*>(&prow[t * 16 + lg * 4]) = o;
    }
    if (lg == 0) {
        pml[(size_t)slot * 128 + row]      = m_i;
        pml[(size_t)slot * 128 + 64 + row] = l_i;
    }
}

// ---------------------------------------------------------------------------
// Merge split-KV partials (R10 verbatim): per (bh, qt) combine nu units.
// ---------------------------------------------------------------------------
__global__ __launch_bounds__(256)
void merge_attn(const ushort_t* __restrict__ py, const float* __restrict__ pml,
                ushort_t* __restrict__ yb) {
    const int bid = blockIdx.x;
    const int bh  = bid >> 5;
    const int qt  = bid & 31;
    const int b   = bh >> 4;
    const int h   = bh & 15;
    const int tid = threadIdx.x;
    const int row = tid >> 2;
    const int d0  = (tid & 3) * 16;

    const int nu    = (qt >> 3) + 1;
    const int sbase = bh * 80 + unit_off(qt);

    float mu[4], lu[4];
    float M = -1e30f;
    #pragma unroll
    for (int u = 0; u < 4; ++u) {
        if (u < nu) {
            mu[u] = pml[(size_t)(sbase + u) * 128 + row];
            lu[u] = pml[(size_t)(sbase + u) * 128 + 64 + row];
            M = fmaxf(M, mu[u]);
        } else { mu[u] = -1e30f; lu[u] = 0.f; }
    }
    float w[4], ltot = 0.f;
    #pragma unroll
    for (int u = 0; u < 4; ++u) {
        w[u] = (u < nu) ? fast_exp2(mu[u] - M) : 0.f;
        ltot += w[u] * lu[u];
    }

    float y[16];
    #pragma unroll
    for (int j = 0; j < 16; ++j) y[j] = 0.f;
    #pragma unroll
    for (int u = 0; u < 4; ++u) {
        if (u < nu) {
            const ushort_t* pr = py + ((size_t)(sbase + u) * 64 + row) * 64 + d0;
            const u16x8 a = *reinterpret_cast<const u16x8*>(&pr[0]);
            const u16x8 c = *reinterpret_cast<const u16x8*>(&pr[8]);
            #pragma unroll
            for (int j = 0; j < 8; ++j) {
                y[j]     += w[u] * f16_f32(a[j]);
                y[8 + j] += w[u] * f16_f32(c[j]);
            }
        }
    }
    const float inv = 1.0f / ltot;
    ushort_t* dst = yb + (size_t)(b * CTXLEN + qt * 64 + row) * DMODEL + h * HDIM + d0;
    u16x8 o0, o1;
    #pragma unroll
    for (int j = 0; j < 8; ++j) {
        o0[j] = f32_f16(y[j] * inv);
        o1[j] = f32_f16(y[8 + j] * inv);
    }
    *reinterpret_cast<u16x8*>(&dst[0]) = o0;
    *reinterpret_cast<u16x8*>(&dst[8]) = o1;
}

// ---------------------------------------------------------------------------
extern "C" void kernel_launch(void* const* d_in, const int* in_sizes, int n_in,
                              void* d_out, int out_size, void* d_ws, size_t ws_size,
                              hipStream_t stream) {
    const float* x      = (const float*)d_in[0];
    const float* w_qkv  = (const float*)d_in[1];
    const float* w_proj = (const float*)d_in[2];
    const float* b_proj = (const float*)d_in[3];
    float* out = (float*)d_out;

    // ws layout (bytes):
    //   wqf f16 [3072,1024]                 @ 0          (6,291,456)
    //   wpf f16 [1024,1024]                 @ 6291456    (2,097,152)
    //   xf  f16 [4096,1024] | yb f16 reuse  @ 8388608    (8,388,608)
    //   qf  f16 [32][2048][64]              @ 16777216   (8,388,608)
    //   kf  f16 [32][2048][64]              @ 25165824   (8,388,608)
    //   vb  f16 [32][2048][64]              @ 33554432   (8,388,608)
    //   vt  f16 [32][64][2048]              @ 41943040   (8,388,608)
    //   py  f16 [2560][64][64]              @ 50331648   (20,971,520)
    //   pml f32 [2560][128]                 @ 71303168   ( 1,310,720)
    char* ws = (char*)d_ws;
    ushort_t* wqf = (ushort_t*)(ws);
    ushort_t* wpf = (ushort_t*)(ws + 6291456);
    ushort_t* xf  = (ushort_t*)(ws + 8388608);
    ushort_t* qf  = (ushort_t*)(ws + 16777216);
    ushort_t* kf  = (ushort_t*)(ws + 25165824);
    ushort_t* vb  = (ushort_t*)(ws + 33554432);
    ushort_t* vt  = (ushort_t*)(ws + 41943040);
    ushort_t* py  = (ushort_t*)(ws + 50331648);
    float*    pml = (float*)   (ws + 71303168);
    ushort_t* yb  = xf;   // reused after qkv GEMM consumed xf

    const dim3 blk(256);

    // one fused convert launch: x, w_qkv, w_proj -> f16
    conv3_f32_f16<<<dim3(2048), blk, 0, stream>>>(
        x, xf, M_TOTAL * DMODEL / 4,
        w_qkv, wqf, 3 * DMODEL * DMODEL / 4,
        w_proj, wpf, DMODEL * DMODEL / 4);

    // qkv = x @ w_qkv^T, single fp16 GEMM (N=3072), epilogue scatters q/k/v
    gemm_f16_nt<true><<<dim3(3 * DMODEL / 128, M_TOTAL / 128), blk, 0, stream>>>(
        xf, wqf, nullptr, nullptr, qf, kf, vb, M_TOTAL, 3 * DMODEL, DMODEL);

    transpose_v<<<dim3(CTXLEN / 64, BATCH * NHEAD), blk, 0, stream>>>(vb, vt);

    // split-KV attention units (pipelined) + merge
    attn_fwd9<<<dim3(2560), blk, 0, stream>>>(qf, kf, vt, py, pml);
    merge_attn<<<dim3(1024), blk, 0, stream>>>(py, pml, yb);

    // out = y @ w_proj^T + b
    gemm_f16_nt<false><<<dim3(DMODEL / 128, M_TOTAL / 128), blk, 0, stream>>>(
        yb, wpf, b_proj, out, nullptr, nullptr, nullptr, M_TOTAL, DMODEL, DMODEL);
}

// Round 14
// 120.945 us; speedup vs baseline: 1.1416x; 1.1038x over previous
//
#include <hip/hip_runtime.h>
#include <hip/hip_bf16.h>

#define DMODEL 1024
#define NHEAD 16
#define HDIM 64
#define CTXLEN 2048
#define BATCH 2
#define M_TOTAL (BATCH * CTXLEN)   // 4096

typedef unsigned short ushort_t;
typedef __attribute__((ext_vector_type(8))) _Float16 f16x8;
typedef __attribute__((ext_vector_type(8))) unsigned short u16x8;
typedef __attribute__((ext_vector_type(4))) float f32x4;
typedef __attribute__((ext_vector_type(4))) unsigned short u16x4;

__device__ __forceinline__ unsigned short f32_f16(float f) {
    return __builtin_bit_cast(unsigned short, (_Float16)f);
}
__device__ __forceinline__ float f16_f32(unsigned short h) {
    return (float)__builtin_bit_cast(_Float16, h);
}
__device__ __forceinline__ float fast_exp2(float x) {
    return __builtin_amdgcn_exp2f(x);
}
__device__ __forceinline__ f32x4 mfma16f(f16x8 a, f16x8 b, f32x4 c) {
    return __builtin_amdgcn_mfma_f32_16x16x32_f16(a, b, c, 0, 0, 0);
}
__device__ __forceinline__ void gload_lds16(const ushort_t* g, ushort_t* l) {
    __builtin_amdgcn_global_load_lds(
        (const __attribute__((address_space(1))) void*)g,
        (__attribute__((address_space(3))) void*)l, 16, 0, 0);
}
// units per q-tile: nu = qt/8+1; slot offset of first unit of qt within a bh
__device__ __forceinline__ int unit_off(int qt) {
    if (qt < 8)  return qt;
    if (qt < 16) return 8 + (qt - 8) * 2;
    if (qt < 24) return 24 + (qt - 16) * 3;
    return 48 + (qt - 24) * 4;
}

// ---------------------------------------------------------------------------
// fused f32 -> f16 convert for 3 arrays (one launch)
// ---------------------------------------------------------------------------
__global__ __launch_bounds__(256)
void conv3_f32_f16(const float* __restrict__ a, ushort_t* __restrict__ da, int na4,
                   const float* __restrict__ b, ushort_t* __restrict__ db, int nb4,
                   const float* __restrict__ c, ushort_t* __restrict__ dc, int nc4) {
    const int n = na4 + nb4 + nc4;
    for (int i = blockIdx.x * blockDim.x + threadIdx.x; i < n;
         i += gridDim.x * blockDim.x) {
        const float* s; ushort_t* d; int j = i;
        if (j < na4) { s = a; d = da; }
        else if (j - na4 < nb4) { j -= na4; s = b; d = db; }
        else { j -= na4 + nb4; s = c; d = dc; }
        const float4 v = reinterpret_cast<const float4*>(s)[j];
        u16x4 o;
        o[0] = f32_f16(v.x); o[1] = f32_f16(v.y);
        o[2] = f32_f16(v.z); o[3] = f32_f16(v.w);
        reinterpret_cast<u16x4*>(d)[j] = o;
    }
}

// ---------------------------------------------------------------------------
// fp16 MFMA GEMM (NT): C = A·B^T. BM=128, BN template (128 or 64), BK=32,
// 4 waves (2x2; per-wave subtile 64 x BN/2). BN=64: 512 blocks for proj
// (2 blocks/CU -> inter-block latency hiding on the serial K-loop).
// ---------------------------------------------------------------------------
template<int BN, bool QKV_EPI>
__global__ __launch_bounds__(256)
void gemm_f16_nt(const ushort_t* __restrict__ A, const ushort_t* __restrict__ B,
                 const float* __restrict__ bias, float* __restrict__ C,
                 ushort_t* __restrict__ qf, ushort_t* __restrict__ kf,
                 ushort_t* __restrict__ vb,
                 int M, int N, int K) {
    constexpr int NF = BN / 32;           // n-frags per wave (4 or 2)
    constexpr int BOFF = 4096;            // A-region size (128 rows x 32 f16)
    __shared__ ushort_t lds[BOFF + BN * 32];

    const int tid  = threadIdx.x;
    const int lane = tid & 63;
    const int wave = tid >> 6;
    const int lc   = lane & 15;
    const int lg   = lane >> 4;
    const int wr   = wave >> 1;
    const int wc   = wave & 1;
    const int row0 = blockIdx.y * 128;
    const int col0 = blockIdx.x * BN;

    const int c0 = tid, c1 = 256 + tid;
    const int r0 = c0 >> 2, l0 = (c0 & 3) ^ ((c0 >> 3) & 3);
    const int r1 = c1 >> 2, l1 = (c1 & 3) ^ ((c1 >> 3) & 3);
    const size_t gaoff0 = (size_t)(row0 + r0) * K + l0 * 8;
    const size_t gaoff1 = (size_t)(row0 + r1) * K + l1 * 8;
    const size_t gboff0 = (size_t)(col0 + r0) * K + l0 * 8;
    const size_t gboff1 = (size_t)(col0 + r1) * K + l1 * 8;   // BN=128 only
    const int ld0 = c0 * 8, ld1 = c1 * 8;

    int aoff[4], boff[NF];
    #pragma unroll
    for (int m = 0; m < 4; ++m) {
        const int ra = wr * 64 + m * 16 + lc;
        aoff[m] = ra * 32 + ((lg ^ ((ra >> 1) & 3)) * 8);
    }
    #pragma unroll
    for (int n = 0; n < NF; ++n) {
        const int rb = wc * (NF * 16) + n * 16 + lc;
        boff[n] = rb * 32 + ((lg ^ ((rb >> 1) & 3)) * 8);
    }

    f32x4 acc[4][NF];
    const f32x4 zero4 = {0.f, 0.f, 0.f, 0.f};
    #pragma unroll
    for (int m = 0; m < 4; ++m)
        #pragma unroll
        for (int n = 0; n < NF; ++n) acc[m][n] = zero4;

    const int NT = K >> 5;

    auto stage = [&](int kt) {
        const int ko = kt * 32;
        gload_lds16(A + gaoff0 + ko, &lds[ld0]);
        gload_lds16(A + gaoff1 + ko, &lds[ld1]);
        gload_lds16(B + gboff0 + ko, &lds[BOFF + ld0]);
        if (BN == 128) gload_lds16(B + gboff1 + ko, &lds[BOFF + ld1]);
    };

    stage(0);
    for (int kt = 0; kt < NT; ++kt) {
        __syncthreads();
        f16x8 fa[4], fb[NF];
        #pragma unroll
        for (int m = 0; m < 4; ++m)
            fa[m] = *reinterpret_cast<const f16x8*>(&lds[aoff[m]]);
        #pragma unroll
        for (int n = 0; n < NF; ++n)
            fb[n] = *reinterpret_cast<const f16x8*>(&lds[BOFF + boff[n]]);
        __syncthreads();
        if (kt + 1 < NT) stage(kt + 1);
        #pragma unroll
        for (int m = 0; m < 4; ++m)
            #pragma unroll
            for (int n = 0; n < NF; ++n)
                acc[m][n] = mfma16f(fa[m], fb[n], acc[m][n]);
    }

    if (!QKV_EPI) {
        #pragma unroll
        for (int m = 0; m < 4; ++m)
            #pragma unroll
            for (int i = 0; i < 4; ++i) {
                const int r = row0 + wr * 64 + m * 16 + lg * 4 + i;
                #pragma unroll
                for (int n = 0; n < NF; ++n) {
                    const int c = col0 + wc * (NF * 16) + n * 16 + lc;
                    C[(size_t)r * N + c] = acc[m][n][i] + bias[c];
                }
            }
    } else {
        #pragma unroll
        for (int m = 0; m < 4; ++m)
            #pragma unroll
            for (int i = 0; i < 4; ++i) {
                const int r = row0 + wr * 64 + m * 16 + lg * 4 + i;
                const int bb = r >> 11;
                const int t  = r & 2047;
                #pragma unroll
                for (int n = 0; n < NF; ++n) {
                    const int cg  = col0 + wc * (NF * 16) + n * 16 + lc;
                    const int sec = cg >> 10;            // 0=q, 1=k, 2=v
                    const int ch  = cg & 1023;
                    const int hh  = ch >> 6;
                    const int d   = ch & 63;
                    const size_t off = (((size_t)(bb * NHEAD + hh)) * CTXLEN + t) * HDIM + d;
                    const unsigned short hv = f32_f16(acc[m][n][i]);
                    if (sec == 0)      qf[off] = hv;
                    else if (sec == 1) kf[off] = hv;
                    else               vb[off] = hv;
                }
            }
    }
}

// ---------------------------------------------------------------------------
// vb [bh][t][d] -> vt [bh][d][t], 64x64 tiles via LDS.
// ---------------------------------------------------------------------------
__global__ __launch_bounds__(256)
void transpose_v(const ushort_t* __restrict__ vb, ushort_t* __restrict__ vt) {
    __shared__ ushort_t T[64][66];
    const int tt = blockIdx.x;
    const int bh = blockIdx.y;
    const int tid = threadIdx.x;
    const int r  = tid >> 2;
    const int c0 = (tid & 3) * 16;

    const ushort_t* src = vb + ((size_t)bh * CTXLEN + tt * 64) * HDIM;
    #pragma unroll
    for (int half = 0; half < 2; ++half) {
        const u16x8 v = *reinterpret_cast<const u16x8*>(&src[(size_t)r * HDIM + c0 + half * 8]);
        #pragma unroll
        for (int j = 0; j < 8; ++j) T[r][c0 + half * 8 + j] = v[j];
    }
    __syncthreads();
    ushort_t* dst = vt + ((size_t)bh * HDIM + r) * CTXLEN + tt * 64 + c0;
    u16x8 o0, o1;
    #pragma unroll
    for (int j = 0; j < 8; ++j) { o0[j] = T[c0 + j][r]; o1[j] = T[c0 + 8 + j][r]; }
    *reinterpret_cast<u16x8*>(&dst[0]) = o0;
    *reinterpret_cast<u16x8*>(&dst[8]) = o1;
}

// ---------------------------------------------------------------------------
// Flash causal attention: R10's attn_fwd7 (split-KV, QBLK=64, units <=8
// steps, grid 2560) + T13 defer-max (skip corr/rescale when the tile max
// didn't grow past m_i + 8; numerics validated in R13's bench).
// ---------------------------------------------------------------------------
#define SCALE_LOG2 11.5415603271f   // 8 * log2(e)

__global__ __launch_bounds__(256)
void attn_fwd7(const ushort_t* __restrict__ qf, const ushort_t* __restrict__ kf,
               const ushort_t* __restrict__ vt,
               ushort_t* __restrict__ py, float* __restrict__ pml) {
    __shared__ ushort_t KH[2][4096];
    __shared__ ushort_t VT[2][4096];
    __shared__ ushort_t Ps[4][16][64];

    const int id    = blockIdx.x;
    const int bh    = id & 31;
    const int u_off = id >> 5;                 // 0..79
    int qt, u;
    if (u_off < 8)       { qt = u_off;                          u = 0; }
    else if (u_off < 24) { const int t = u_off - 8;  qt = 8  + (t >> 1); u = t & 1; }
    else if (u_off < 48) { const int t = u_off - 24; const int q3 = t / 3; qt = 16 + q3; u = t - q3 * 3; }
    else                 { const int t = u_off - 48; qt = 24 + (t >> 2); u = t & 3; }
    const int total = qt + 1;
    const int nu    = (qt >> 3) + 1;
    const int base  = total / nu, rem = total % nu;
    const int kb0   = u * base + (u < rem ? u : rem);
    const int len   = base + (u < rem ? 1 : 0);
    const int slot  = bh * 80 + u_off;

    const int tid  = threadIdx.x;
    const int wave = tid >> 6;
    const int lane = tid & 63;
    const int lc   = lane & 15;
    const int lg   = lane >> 4;

    const ushort_t* kfb = kf + (size_t)bh * CTXLEN * HDIM;
    const ushort_t* vtb = vt + (size_t)bh * HDIM * CTXLEN;

    const int cA = tid, cB = 256 + tid;
    const int rA = cA >> 3, sgA = (cA & 7) ^ (rA & 7);
    const int rB = cB >> 3, sgB = (cB & 7) ^ (rB & 7);

    auto stage = [&](int kb, int buf) {
        const size_t koff = (size_t)(kb * 64);
        gload_lds16(kfb + (koff + rA) * HDIM + sgA * 8, &KH[buf][cA * 8]);
        gload_lds16(kfb + (koff + rB) * HDIM + sgB * 8, &KH[buf][cB * 8]);
        gload_lds16(vtb + (size_t)rA * CTXLEN + kb * 64 + sgA * 8, &VT[buf][cA * 8]);
        gload_lds16(vtb + (size_t)rB * CTXLEN + kb * 64 + sgB * 8, &VT[buf][cB * 8]);
    };

    // Q fragments: q row = qt*64 + wave*16 + lc
    const size_t qrow = (size_t)bh * CTXLEN + qt * 64 + wave * 16 + lc;
    f16x8 qfr[2];
    #pragma unroll
    for (int ds = 0; ds < 2; ++ds)
        qfr[ds] = *reinterpret_cast<const f16x8*>(&qf[qrow * HDIM + ds * 32 + lg * 8]);

    const f32x4 zero4 = {0.f, 0.f, 0.f, 0.f};
    f32x4 yacc[4];   // y^T: d = t*16+lg*4+i, q = lc
    #pragma unroll
    for (int t = 0; t < 4; ++t) yacc[t] = zero4;
    float m_i = -1e30f, l_i = 0.f;

    stage(kb0, 0);
    __syncthreads();

    int cur = 0;
    for (int s = 0; s < len; ++s) {
        const int kb = kb0 + s;
        if (s + 1 < len) stage(kb + 1, cur ^ 1);

        // K fragments (swizzled)
        f16x8 kfr[4][2];
        #pragma unroll
        for (int tc = 0; tc < 4; ++tc) {
            const int rk = tc * 16 + lc;
            #pragma unroll
            for (int ds = 0; ds < 2; ++ds) {
                const int a = rk * 64 + (((ds * 4 + lg) ^ (rk & 7)) * 8);
                kfr[tc][ds] = *reinterpret_cast<const f16x8*>(&KH[cur][a]);
            }
        }
        // V^T fragments (swizzled)
        f16x8 vf[4][2];
        #pragma unroll
        for (int t = 0; t < 4; ++t) {
            const int rv = t * 16 + lc;
            #pragma unroll
            for (int ks = 0; ks < 2; ++ks) {
                const int a = rv * 64 + (((ks * 4 + lg) ^ (rv & 7)) * 8);
                vf[t][ks] = *reinterpret_cast<const f16x8*>(&VT[cur][a]);
            }
        }

        // S^T = K Q^T : D[k = tc*16+lg*4+i][q = lc]
        f32x4 sacc[4];
        #pragma unroll
        for (int tc = 0; tc < 4; ++tc) sacc[tc] = zero4;
        __builtin_amdgcn_s_setprio(1);
        #pragma unroll
        for (int tc = 0; tc < 4; ++tc)
            #pragma unroll
            for (int ds = 0; ds < 2; ++ds)
                sacc[tc] = mfma16f(kfr[tc][ds], qfr[ds], sacc[tc]);
        __builtin_amdgcn_s_setprio(0);

        const bool diag = (kb == qt);
        const int q_loc = wave * 16 + lc;
        float p[4][4];
        #pragma unroll
        for (int tc = 0; tc < 4; ++tc)
            #pragma unroll
            for (int i = 0; i < 4; ++i) {
                float uu = sacc[tc][i] * SCALE_LOG2;
                if (diag && (tc * 16 + lg * 4 + i) > q_loc) uu = -1e30f;
                p[tc][i] = uu;
            }
        float mx = p[0][0];
        #pragma unroll
        for (int tc = 0; tc < 4; ++tc)
            #pragma unroll
            for (int i = 0; i < 4; ++i) mx = fmaxf(mx, p[tc][i]);
        mx = fmaxf(mx, __shfl_xor(mx, 16));
        mx = fmaxf(mx, __shfl_xor(mx, 32));

        if (__all(mx <= m_i + 8.0f)) {
            // defer-max: keep m_i, skip corr/rescale (p <= 2^8, f16-safe)
            float psum = 0.f;
            #pragma unroll
            for (int tc = 0; tc < 4; ++tc)
                #pragma unroll
                for (int i = 0; i < 4; ++i) {
                    const float e = fast_exp2(p[tc][i] - m_i);
                    p[tc][i] = e;
                    psum += e;
                }
            psum += __shfl_xor(psum, 16);
            psum += __shfl_xor(psum, 32);
            l_i += psum;
        } else {
            const float mnew = fmaxf(m_i, mx);
            const float corr = fast_exp2(m_i - mnew);
            float psum = 0.f;
            #pragma unroll
            for (int tc = 0; tc < 4; ++tc)
                #pragma unroll
                for (int i = 0; i < 4; ++i) {
                    const float e = fast_exp2(p[tc][i] - mnew);
                    p[tc][i] = e;
                    psum += e;
                }
            psum += __shfl_xor(psum, 16);
            psum += __shfl_xor(psum, 32);
            l_i = l_i * corr + psum;
            m_i = mnew;
            #pragma unroll
            for (int t = 0; t < 4; ++t) yacc[t] *= corr;
        }

        // P -> Ps (wave-private, swizzled, u16x4 chunks)
        #pragma unroll
        for (int tc = 0; tc < 4; ++tc) {
            const int eb = tc * 16 + lg * 4;
            const int se = ((((eb >> 3) ^ (lc & 7)) << 3) | (eb & 7));
            u16x4 pk;
            #pragma unroll
            for (int i = 0; i < 4; ++i) pk[i] = f32_f16(p[tc][i]);
            *reinterpret_cast<u16x4*>(&Ps[wave][lc][se]) = pk;
        }
        f16x8 pa[2];
        #pragma unroll
        for (int ks = 0; ks < 2; ++ks) {
            const int sl = ((ks * 4 + lg) ^ (lc & 7)) << 3;
            pa[ks] = *reinterpret_cast<const f16x8*>(&Ps[wave][lc][sl]);
        }
        // y^T += V^T P
        __builtin_amdgcn_s_setprio(1);
        #pragma unroll
        for (int t = 0; t < 4; ++t)
            #pragma unroll
            for (int ks = 0; ks < 2; ++ks)
                yacc[t] = mfma16f(vf[t][ks], pa[ks], yacc[t]);
        __builtin_amdgcn_s_setprio(0);

        __syncthreads();
        cur ^= 1;
    }

    // partial epilogue: unnormalized y (f16) + m,l (f32)
    const int row = wave * 16 + lc;
    ushort_t* prow = py + ((size_t)slot * 64 + row) * 64;
    #pragma unroll
    for (int t = 0; t < 4; ++t) {
        u16x4 o;
        #pragma unroll
        for (int i = 0; i < 4; ++i) o[i] = f32_f16(yacc[t][i]);
        *reinterpret_cast<u16x4*>(&prow[t * 16 + lg * 4]) = o;
    }
    if (lg == 0) {
        pml[(size_t)slot * 128 + row]      = m_i;
        pml[(size_t)slot * 128 + 64 + row] = l_i;
    }
}

// ---------------------------------------------------------------------------
// Merge split-KV partials: per (bh, qt) combine nu units -> yb f16.
// ---------------------------------------------------------------------------
__global__ __launch_bounds__(256)
void merge_attn(const ushort_t* __restrict__ py, const float* __restrict__ pml,
                ushort_t* __restrict__ yb) {
    const int bid = blockIdx.x;
    const int bh  = bid >> 5;
    const int qt  = bid & 31;
    const int b   = bh >> 4;
    const int h   = bh & 15;
    const int tid = threadIdx.x;
    const int row = tid >> 2;
    const int d0  = (tid & 3) * 16;

    const int nu    = (qt >> 3) + 1;
    const int sbase = bh * 80 + unit_off(qt);

    float mu[4], lu[4];
    float M = -1e30f;
    #pragma unroll
    for (int u = 0; u < 4; ++u) {
        if (u < nu) {
            mu[u] = pml[(size_t)(sbase + u) * 128 + row];
            lu[u] = pml[(size_t)(sbase + u) * 128 + 64 + row];
            M = fmaxf(M, mu[u]);
        } else { mu[u] = -1e30f; lu[u] = 0.f; }
    }
    float w[4], ltot = 0.f;
    #pragma unroll
    for (int u = 0; u < 4; ++u) {
        w[u] = (u < nu) ? fast_exp2(mu[u] - M) : 0.f;
        ltot += w[u] * lu[u];
    }

    float y[16];
    #pragma unroll
    for (int j = 0; j < 16; ++j) y[j] = 0.f;
    #pragma unroll
    for (int u = 0; u < 4; ++u) {
        if (u < nu) {
            const ushort_t* pr = py + ((size_t)(sbase + u) * 64 + row) * 64 + d0;
            const u16x8 a = *reinterpret_cast<const u16x8*>(&pr[0]);
            const u16x8 c = *reinterpret_cast<const u16x8*>(&pr[8]);
            #pragma unroll
            for (int j = 0; j < 8; ++j) {
                y[j]     += w[u] * f16_f32(a[j]);
                y[8 + j] += w[u] * f16_f32(c[j]);
            }
        }
    }
    const float inv = 1.0f / ltot;
    ushort_t* dst = yb + (size_t)(b * CTXLEN + qt * 64 + row) * DMODEL + h * HDIM + d0;
    u16x8 o0, o1;
    #pragma unroll
    for (int j = 0; j < 8; ++j) {
        o0[j] = f32_f16(y[j] * inv);
        o1[j] = f32_f16(y[8 + j] * inv);
    }
    *reinterpret_cast<u16x8*>(&dst[0]) = o0;
    *reinterpret_cast<u16x8*>(&dst[8]) = o1;
}

// ---------------------------------------------------------------------------
extern "C" void kernel_launch(void* const* d_in, const int* in_sizes, int n_in,
                              void* d_out, int out_size, void* d_ws, size_t ws_size,
                              hipStream_t stream) {
    const float* x      = (const float*)d_in[0];
    const float* w_qkv  = (const float*)d_in[1];
    const float* w_proj = (const float*)d_in[2];
    const float* b_proj = (const float*)d_in[3];
    float* out = (float*)d_out;

    // ws layout (bytes):
    //   wqf f16 [3072,1024]                 @ 0          (6,291,456)
    //   wpf f16 [1024,1024]                 @ 6291456    (2,097,152)
    //   xf  f16 [4096,1024] | yb f16 reuse  @ 8388608    (8,388,608)
    //   qf  f16 [32][2048][64]              @ 16777216   (8,388,608)
    //   kf  f16 [32][2048][64]              @ 25165824   (8,388,608)
    //   vb  f16 [32][2048][64]              @ 33554432   (8,388,608)
    //   vt  f16 [32][64][2048]              @ 41943040   (8,388,608)
    //   py  f16 [2560][64][64]              @ 50331648   (20,971,520)
    //   pml f32 [2560][128]                 @ 71303168   ( 1,310,720)
    char* ws = (char*)d_ws;
    ushort_t* wqf = (ushort_t*)(ws);
    ushort_t* wpf = (ushort_t*)(ws + 6291456);
    ushort_t* xf  = (ushort_t*)(ws + 8388608);
    ushort_t* qf  = (ushort_t*)(ws + 16777216);
    ushort_t* kf  = (ushort_t*)(ws + 25165824);
    ushort_t* vb  = (ushort_t*)(ws + 33554432);
    ushort_t* vt  = (ushort_t*)(ws + 41943040);
    ushort_t* py  = (ushort_t*)(ws + 50331648);
    float*    pml = (float*)   (ws + 71303168);
    ushort_t* yb  = xf;   // reused after qkv GEMM consumed xf

    const dim3 blk(256);

    // one fused convert launch: x, w_qkv, w_proj -> f16
    conv3_f32_f16<<<dim3(2048), blk, 0, stream>>>(
        x, xf, M_TOTAL * DMODEL / 4,
        w_qkv, wqf, 3 * DMODEL * DMODEL / 4,
        w_proj, wpf, DMODEL * DMODEL / 4);

    // qkv = x @ w_qkv^T, single fp16 GEMM (N=3072), epilogue scatters q/k/v
    gemm_f16_nt<128, true><<<dim3(3 * DMODEL / 128, M_TOTAL / 128), blk, 0, stream>>>(
        xf, wqf, nullptr, nullptr, qf, kf, vb, M_TOTAL, 3 * DMODEL, DMODEL);

    transpose_v<<<dim3(CTXLEN / 64, BATCH * NHEAD), blk, 0, stream>>>(vb, vt);

    // split-KV attention units + merge
    attn_fwd7<<<dim3(2560), blk, 0, stream>>>(qf, kf, vt, py, pml);
    merge_attn<<<dim3(1024), blk, 0, stream>>>(py, pml, yb);

    // out = y @ w_proj^T + b  — BN=64 tiles -> 512 blocks (2/CU)
    gemm_f16_nt<64, false><<<dim3(DMODEL / 64, M_TOTAL / 128), blk, 0, stream>>>(
        yb, wpf, b_proj, out, nullptr, nullptr, nullptr, M_TOTAL, DMODEL, DMODEL);
}

// Round 15
// 120.588 us; speedup vs baseline: 1.1450x; 1.0030x over previous
//
#include <hip/hip_runtime.h>
#include <hip/hip_bf16.h>

#define DMODEL 1024
#define NHEAD 16
#define HDIM 64
#define CTXLEN 2048
#define BATCH 2
#define M_TOTAL (BATCH * CTXLEN)   // 4096

typedef unsigned short ushort_t;
typedef __attribute__((ext_vector_type(8))) _Float16 f16x8;
typedef __attribute__((ext_vector_type(8))) unsigned short u16x8;
typedef __attribute__((ext_vector_type(4))) float f32x4;
typedef __attribute__((ext_vector_type(4))) unsigned short u16x4;

__device__ __forceinline__ unsigned short f32_f16(float f) {
    return __builtin_bit_cast(unsigned short, (_Float16)f);
}
__device__ __forceinline__ float f16_f32(unsigned short h) {
    return (float)__builtin_bit_cast(_Float16, h);
}
__device__ __forceinline__ float fast_exp2(float x) {
    return __builtin_amdgcn_exp2f(x);
}
__device__ __forceinline__ f32x4 mfma16f(f16x8 a, f16x8 b, f32x4 c) {
    return __builtin_amdgcn_mfma_f32_16x16x32_f16(a, b, c, 0, 0, 0);
}
__device__ __forceinline__ void gload_lds16(const ushort_t* g, ushort_t* l) {
    __builtin_amdgcn_global_load_lds(
        (const __attribute__((address_space(1))) void*)g,
        (__attribute__((address_space(3))) void*)l, 16, 0, 0);
}
// units per q-tile: nu = qt/8+1; slot offset of first unit of qt within a bh
__device__ __forceinline__ int unit_off(int qt) {
    if (qt < 8)  return qt;
    if (qt < 16) return 8 + (qt - 8) * 2;
    if (qt < 24) return 24 + (qt - 16) * 3;
    return 48 + (qt - 24) * 4;
}

// ---------------------------------------------------------------------------
// fused f32 -> f16 convert for 3 arrays (one launch)
// ---------------------------------------------------------------------------
__global__ __launch_bounds__(256)
void conv3_f32_f16(const float* __restrict__ a, ushort_t* __restrict__ da, int na4,
                   const float* __restrict__ b, ushort_t* __restrict__ db, int nb4,
                   const float* __restrict__ c, ushort_t* __restrict__ dc, int nc4) {
    const int n = na4 + nb4 + nc4;
    for (int i = blockIdx.x * blockDim.x + threadIdx.x; i < n;
         i += gridDim.x * blockDim.x) {
        const float* s; ushort_t* d; int j = i;
        if (j < na4) { s = a; d = da; }
        else if (j - na4 < nb4) { j -= na4; s = b; d = db; }
        else { j -= na4 + nb4; s = c; d = dc; }
        const float4 v = reinterpret_cast<const float4*>(s)[j];
        u16x4 o;
        o[0] = f32_f16(v.x); o[1] = f32_f16(v.y);
        o[2] = f32_f16(v.z); o[3] = f32_f16(v.w);
        reinterpret_cast<u16x4*>(d)[j] = o;
    }
}

// ---------------------------------------------------------------------------
// fp16 MFMA GEMM (NT): C = A·B^T. BM=128, BN template (128 or 64), BK=32,
// 4 waves (2x2; per-wave subtile 64 x BN/2). BN=64: 512 blocks for proj.
// ---------------------------------------------------------------------------
template<int BN, bool QKV_EPI>
__global__ __launch_bounds__(256)
void gemm_f16_nt(const ushort_t* __restrict__ A, const ushort_t* __restrict__ B,
                 const float* __restrict__ bias, float* __restrict__ C,
                 ushort_t* __restrict__ qf, ushort_t* __restrict__ kf,
                 ushort_t* __restrict__ vb,
                 int M, int N, int K) {
    constexpr int NF = BN / 32;           // n-frags per wave (4 or 2)
    constexpr int BOFF = 4096;            // A-region size (128 rows x 32 f16)
    __shared__ ushort_t lds[BOFF + BN * 32];

    const int tid  = threadIdx.x;
    const int lane = tid & 63;
    const int wave = tid >> 6;
    const int lc   = lane & 15;
    const int lg   = lane >> 4;
    const int wr   = wave >> 1;
    const int wc   = wave & 1;
    const int row0 = blockIdx.y * 128;
    const int col0 = blockIdx.x * BN;

    const int c0 = tid, c1 = 256 + tid;
    const int r0 = c0 >> 2, l0 = (c0 & 3) ^ ((c0 >> 3) & 3);
    const int r1 = c1 >> 2, l1 = (c1 & 3) ^ ((c1 >> 3) & 3);
    const size_t gaoff0 = (size_t)(row0 + r0) * K + l0 * 8;
    const size_t gaoff1 = (size_t)(row0 + r1) * K + l1 * 8;
    const size_t gboff0 = (size_t)(col0 + r0) * K + l0 * 8;
    const size_t gboff1 = (size_t)(col0 + r1) * K + l1 * 8;   // BN=128 only
    const int ld0 = c0 * 8, ld1 = c1 * 8;

    int aoff[4], boff[NF];
    #pragma unroll
    for (int m = 0; m < 4; ++m) {
        const int ra = wr * 64 + m * 16 + lc;
        aoff[m] = ra * 32 + ((lg ^ ((ra >> 1) & 3)) * 8);
    }
    #pragma unroll
    for (int n = 0; n < NF; ++n) {
        const int rb = wc * (NF * 16) + n * 16 + lc;
        boff[n] = rb * 32 + ((lg ^ ((rb >> 1) & 3)) * 8);
    }

    f32x4 acc[4][NF];
    const f32x4 zero4 = {0.f, 0.f, 0.f, 0.f};
    #pragma unroll
    for (int m = 0; m < 4; ++m)
        #pragma unroll
        for (int n = 0; n < NF; ++n) acc[m][n] = zero4;

    const int NT = K >> 5;

    auto stage = [&](int kt) {
        const int ko = kt * 32;
        gload_lds16(A + gaoff0 + ko, &lds[ld0]);
        gload_lds16(A + gaoff1 + ko, &lds[ld1]);
        gload_lds16(B + gboff0 + ko, &lds[BOFF + ld0]);
        if (BN == 128) gload_lds16(B + gboff1 + ko, &lds[BOFF + ld1]);
    };

    stage(0);
    for (int kt = 0; kt < NT; ++kt) {
        __syncthreads();
        f16x8 fa[4], fb[NF];
        #pragma unroll
        for (int m = 0; m < 4; ++m)
            fa[m] = *reinterpret_cast<const f16x8*>(&lds[aoff[m]]);
        #pragma unroll
        for (int n = 0; n < NF; ++n)
            fb[n] = *reinterpret_cast<const f16x8*>(&lds[BOFF + boff[n]]);
        __syncthreads();
        if (kt + 1 < NT) stage(kt + 1);
        #pragma unroll
        for (int m = 0; m < 4; ++m)
            #pragma unroll
            for (int n = 0; n < NF; ++n)
                acc[m][n] = mfma16f(fa[m], fb[n], acc[m][n]);
    }

    if (!QKV_EPI) {
        #pragma unroll
        for (int m = 0; m < 4; ++m)
            #pragma unroll
            for (int i = 0; i < 4; ++i) {
                const int r = row0 + wr * 64 + m * 16 + lg * 4 + i;
                #pragma unroll
                for (int n = 0; n < NF; ++n) {
                    const int c = col0 + wc * (NF * 16) + n * 16 + lc;
                    C[(size_t)r * N + c] = acc[m][n][i] + bias[c];
                }
            }
    } else {
        #pragma unroll
        for (int m = 0; m < 4; ++m)
            #pragma unroll
            for (int i = 0; i < 4; ++i) {
                const int r = row0 + wr * 64 + m * 16 + lg * 4 + i;
                const int bb = r >> 11;
                const int t  = r & 2047;
                #pragma unroll
                for (int n = 0; n < NF; ++n) {
                    const int cg  = col0 + wc * (NF * 16) + n * 16 + lc;
                    const int sec = cg >> 10;            // 0=q, 1=k, 2=v
                    const int ch  = cg & 1023;
                    const int hh  = ch >> 6;
                    const int d   = ch & 63;
                    const size_t off = (((size_t)(bb * NHEAD + hh)) * CTXLEN + t) * HDIM + d;
                    const unsigned short hv = f32_f16(acc[m][n][i]);
                    if (sec == 0)      qf[off] = hv;
                    else if (sec == 1) kf[off] = hv;
                    else               vb[off] = hv;
                }
            }
    }
}

// ---------------------------------------------------------------------------
// vb [bh][t][d] -> vt [bh][d][t], 64x64 tiles via LDS.
// ---------------------------------------------------------------------------
__global__ __launch_bounds__(256)
void transpose_v(const ushort_t* __restrict__ vb, ushort_t* __restrict__ vt) {
    __shared__ ushort_t T[64][66];
    const int tt = blockIdx.x;
    const int bh = blockIdx.y;
    const int tid = threadIdx.x;
    const int r  = tid >> 2;
    const int c0 = (tid & 3) * 16;

    const ushort_t* src = vb + ((size_t)bh * CTXLEN + tt * 64) * HDIM;
    #pragma unroll
    for (int half = 0; half < 2; ++half) {
        const u16x8 v = *reinterpret_cast<const u16x8*>(&src[(size_t)r * HDIM + c0 + half * 8]);
        #pragma unroll
        for (int j = 0; j < 8; ++j) T[r][c0 + half * 8 + j] = v[j];
    }
    __syncthreads();
    ushort_t* dst = vt + ((size_t)bh * HDIM + r) * CTXLEN + tt * 64 + c0;
    u16x8 o0, o1;
    #pragma unroll
    for (int j = 0; j < 8; ++j) { o0[j] = T[c0 + j][r]; o1[j] = T[c0 + 8 + j][r]; }
    *reinterpret_cast<u16x8*>(&dst[0]) = o0;
    *reinterpret_cast<u16x8*>(&dst[8]) = o1;
}

// ---------------------------------------------------------------------------
// Flash causal attention: split-KV (QBLK=64, units <=8 steps, grid 2560)
// + T13 defer-max + LPT dispatch (u_off = 79 - id>>5: longest units launch
// FIRST so the tail is 1-2-step crumbs that backfill; fixes the anti-LPT
// ordering that capped resident blocks at ~2/CU) + diag-masking hoisted to
// a wave-uniform branch (85% of steps skip the 32 mask ops).
// ---------------------------------------------------------------------------
#define SCALE_LOG2 11.5415603271f   // 8 * log2(e)

__global__ __launch_bounds__(256)
void attn_fwd7(const ushort_t* __restrict__ qf, const ushort_t* __restrict__ kf,
               const ushort_t* __restrict__ vt,
               ushort_t* __restrict__ py, float* __restrict__ pml) {
    __shared__ ushort_t KH[2][4096];
    __shared__ ushort_t VT[2][4096];
    __shared__ ushort_t Ps[4][16][64];

    const int id    = blockIdx.x;
    const int bh    = id & 31;
    const int u_off = 79 - (id >> 5);          // LPT: longest units first
    int qt, u;
    if (u_off < 8)       { qt = u_off;                          u = 0; }
    else if (u_off < 24) { const int t = u_off - 8;  qt = 8  + (t >> 1); u = t & 1; }
    else if (u_off < 48) { const int t = u_off - 24; const int q3 = t / 3; qt = 16 + q3; u = t - q3 * 3; }
    else                 { const int t = u_off - 48; qt = 24 + (t >> 2); u = t & 3; }
    const int total = qt + 1;
    const int nu    = (qt >> 3) + 1;
    const int base  = total / nu, rem = total % nu;
    const int kb0   = u * base + (u < rem ? u : rem);
    const int len   = base + (u < rem ? 1 : 0);
    const int slot  = bh * 80 + u_off;

    const int tid  = threadIdx.x;
    const int wave = tid >> 6;
    const int lane = tid & 63;
    const int lc   = lane & 15;
    const int lg   = lane >> 4;

    const ushort_t* kfb = kf + (size_t)bh * CTXLEN * HDIM;
    const ushort_t* vtb = vt + (size_t)bh * HDIM * CTXLEN;

    const int cA = tid, cB = 256 + tid;
    const int rA = cA >> 3, sgA = (cA & 7) ^ (rA & 7);
    const int rB = cB >> 3, sgB = (cB & 7) ^ (rB & 7);

    auto stage = [&](int kb, int buf) {
        const size_t koff = (size_t)(kb * 64);
        gload_lds16(kfb + (koff + rA) * HDIM + sgA * 8, &KH[buf][cA * 8]);
        gload_lds16(kfb + (koff + rB) * HDIM + sgB * 8, &KH[buf][cB * 8]);
        gload_lds16(vtb + (size_t)rA * CTXLEN + kb * 64 + sgA * 8, &VT[buf][cA * 8]);
        gload_lds16(vtb + (size_t)rB * CTXLEN + kb * 64 + sgB * 8, &VT[buf][cB * 8]);
    };

    // Q fragments: q row = qt*64 + wave*16 + lc
    const size_t qrow = (size_t)bh * CTXLEN + qt * 64 + wave * 16 + lc;
    f16x8 qfr[2];
    #pragma unroll
    for (int ds = 0; ds < 2; ++ds)
        qfr[ds] = *reinterpret_cast<const f16x8*>(&qf[qrow * HDIM + ds * 32 + lg * 8]);

    const f32x4 zero4 = {0.f, 0.f, 0.f, 0.f};
    f32x4 yacc[4];   // y^T: d = t*16+lg*4+i, q = lc
    #pragma unroll
    for (int t = 0; t < 4; ++t) yacc[t] = zero4;
    float m_i = -1e30f, l_i = 0.f;

    stage(kb0, 0);
    __syncthreads();

    int cur = 0;
    for (int s = 0; s < len; ++s) {
        const int kb = kb0 + s;
        if (s + 1 < len) stage(kb + 1, cur ^ 1);

        // K fragments (swizzled)
        f16x8 kfr[4][2];
        #pragma unroll
        for (int tc = 0; tc < 4; ++tc) {
            const int rk = tc * 16 + lc;
            #pragma unroll
            for (int ds = 0; ds < 2; ++ds) {
                const int a = rk * 64 + (((ds * 4 + lg) ^ (rk & 7)) * 8);
                kfr[tc][ds] = *reinterpret_cast<const f16x8*>(&KH[cur][a]);
            }
        }
        // V^T fragments (swizzled)
        f16x8 vf[4][2];
        #pragma unroll
        for (int t = 0; t < 4; ++t) {
            const int rv = t * 16 + lc;
            #pragma unroll
            for (int ks = 0; ks < 2; ++ks) {
                const int a = rv * 64 + (((ks * 4 + lg) ^ (rv & 7)) * 8);
                vf[t][ks] = *reinterpret_cast<const f16x8*>(&VT[cur][a]);
            }
        }

        // S^T = K Q^T : D[k = tc*16+lg*4+i][q = lc]
        f32x4 sacc[4];
        #pragma unroll
        for (int tc = 0; tc < 4; ++tc) sacc[tc] = zero4;
        __builtin_amdgcn_s_setprio(1);
        #pragma unroll
        for (int tc = 0; tc < 4; ++tc)
            #pragma unroll
            for (int ds = 0; ds < 2; ++ds)
                sacc[tc] = mfma16f(kfr[tc][ds], qfr[ds], sacc[tc]);
        __builtin_amdgcn_s_setprio(0);

        float p[4][4];
        #pragma unroll
        for (int tc = 0; tc < 4; ++tc)
            #pragma unroll
            for (int i = 0; i < 4; ++i)
                p[tc][i] = sacc[tc][i] * SCALE_LOG2;
        if (kb == qt) {   // diagonal tile only: apply causal mask (wave-uniform)
            const int q_loc = wave * 16 + lc;
            #pragma unroll
            for (int tc = 0; tc < 4; ++tc)
                #pragma unroll
                for (int i = 0; i < 4; ++i)
                    if ((tc * 16 + lg * 4 + i) > q_loc) p[tc][i] = -1e30f;
        }
        float mx = p[0][0];
        #pragma unroll
        for (int tc = 0; tc < 4; ++tc)
            #pragma unroll
            for (int i = 0; i < 4; ++i) mx = fmaxf(mx, p[tc][i]);
        mx = fmaxf(mx, __shfl_xor(mx, 16));
        mx = fmaxf(mx, __shfl_xor(mx, 32));

        if (__all(mx <= m_i + 8.0f)) {
            // defer-max: keep m_i, skip corr/rescale (p <= 2^8, f16-safe)
            float psum = 0.f;
            #pragma unroll
            for (int tc = 0; tc < 4; ++tc)
                #pragma unroll
                for (int i = 0; i < 4; ++i) {
                    const float e = fast_exp2(p[tc][i] - m_i);
                    p[tc][i] = e;
                    psum += e;
                }
            psum += __shfl_xor(psum, 16);
            psum += __shfl_xor(psum, 32);
            l_i += psum;
        } else {
            const float mnew = fmaxf(m_i, mx);
            const float corr = fast_exp2(m_i - mnew);
            float psum = 0.f;
            #pragma unroll
            for (int tc = 0; tc < 4; ++tc)
                #pragma unroll
                for (int i = 0; i < 4; ++i) {
                    const float e = fast_exp2(p[tc][i] - mnew);
                    p[tc][i] = e;
                    psum += e;
                }
            psum += __shfl_xor(psum, 16);
            psum += __shfl_xor(psum, 32);
            l_i = l_i * corr + psum;
            m_i = mnew;
            #pragma unroll
            for (int t = 0; t < 4; ++t) yacc[t] *= corr;
        }

        // P -> Ps (wave-private, swizzled, u16x4 chunks)
        #pragma unroll
        for (int tc = 0; tc < 4; ++tc) {
            const int eb = tc * 16 + lg * 4;
            const int se = ((((eb >> 3) ^ (lc & 7)) << 3) | (eb & 7));
            u16x4 pk;
            #pragma unroll
            for (int i = 0; i < 4; ++i) pk[i] = f32_f16(p[tc][i]);
            *reinterpret_cast<u16x4*>(&Ps[wave][lc][se]) = pk;
        }
        f16x8 pa[2];
        #pragma unroll
        for (int ks = 0; ks < 2; ++ks) {
            const int sl = ((ks * 4 + lg) ^ (lc & 7)) << 3;
            pa[ks] = *reinterpret_cast<const f16x8*>(&Ps[wave][lc][sl]);
        }
        // y^T += V^T P
        __builtin_amdgcn_s_setprio(1);
        #pragma unroll
        for (int t = 0; t < 4; ++t)
            #pragma unroll
            for (int ks = 0; ks < 2; ++ks)
                yacc[t] = mfma16f(vf[t][ks], pa[ks], yacc[t]);
        __builtin_amdgcn_s_setprio(0);

        __syncthreads();
        cur ^= 1;
    }

    // partial epilogue: unnormalized y (f16) + m,l (f32)
    const int row = wave * 16 + lc;
    ushort_t* prow = py + ((size_t)slot * 64 + row) * 64;
    #pragma unroll
    for (int t = 0; t < 4; ++t) {
        u16x4 o;
        #pragma unroll
        for (int i = 0; i < 4; ++i) o[i] = f32_f16(yacc[t][i]);
        *reinterpret_cast<u16x4*>(&prow[t * 16 + lg * 4]) = o;
    }
    if (lg == 0) {
        pml[(size_t)slot * 128 + row]      = m_i;
        pml[(size_t)slot * 128 + 64 + row] = l_i;
    }
}

// ---------------------------------------------------------------------------
// Merge split-KV partials: per (bh, qt) combine nu units -> yb f16.
// ---------------------------------------------------------------------------
__global__ __launch_bounds__(256)
void merge_attn(const ushort_t* __restrict__ py, const float* __restrict__ pml,
                ushort_t* __restrict__ yb) {
    const int bid = blockIdx.x;
    const int bh  = bid >> 5;
    const int qt  = bid & 31;
    const int b   = bh >> 4;
    const int h   = bh & 15;
    const int tid = threadIdx.x;
    const int row = tid >> 2;
    const int d0  = (tid & 3) * 16;

    const int nu    = (qt >> 3) + 1;
    const int sbase = bh * 80 + unit_off(qt);

    float mu[4], lu[4];
    float M = -1e30f;
    #pragma unroll
    for (int u = 0; u < 4; ++u) {
        if (u < nu) {
            mu[u] = pml[(size_t)(sbase + u) * 128 + row];
            lu[u] = pml[(size_t)(sbase + u) * 128 + 64 + row];
            M = fmaxf(M, mu[u]);
        } else { mu[u] = -1e30f; lu[u] = 0.f; }
    }
    float w[4], ltot = 0.f;
    #pragma unroll
    for (int u = 0; u < 4; ++u) {
        w[u] = (u < nu) ? fast_exp2(mu[u] - M) : 0.f;
        ltot += w[u] * lu[u];
    }

    float y[16];
    #pragma unroll
    for (int j = 0; j < 16; ++j) y[j] = 0.f;
    #pragma unroll
    for (int u = 0; u < 4; ++u) {
        if (u < nu) {
            const ushort_t* pr = py + ((size_t)(sbase + u) * 64 + row) * 64 + d0;
            const u16x8 a = *reinterpret_cast<const u16x8*>(&pr[0]);
            const u16x8 c = *reinterpret_cast<const u16x8*>(&pr[8]);
            #pragma unroll
            for (int j = 0; j < 8; ++j) {
                y[j]     += w[u] * f16_f32(a[j]);
                y[8 + j] += w[u] * f16_f32(c[j]);
            }
        }
    }
    const float inv = 1.0f / ltot;
    ushort_t* dst = yb + (size_t)(b * CTXLEN + qt * 64 + row) * DMODEL + h * HDIM + d0;
    u16x8 o0, o1;
    #pragma unroll
    for (int j = 0; j < 8; ++j) {
        o0[j] = f32_f16(y[j] * inv);
        o1[j] = f32_f16(y[8 + j] * inv);
    }
    *reinterpret_cast<u16x8*>(&dst[0]) = o0;
    *reinterpret_cast<u16x8*>(&dst[8]) = o1;
}

// ---------------------------------------------------------------------------
extern "C" void kernel_launch(void* const* d_in, const int* in_sizes, int n_in,
                              void* d_out, int out_size, void* d_ws, size_t ws_size,
                              hipStream_t stream) {
    const float* x      = (const float*)d_in[0];
    const float* w_qkv  = (const float*)d_in[1];
    const float* w_proj = (const float*)d_in[2];
    const float* b_proj = (const float*)d_in[3];
    float* out = (float*)d_out;

    // ws layout (bytes):
    //   wqf f16 [3072,1024]                 @ 0          (6,291,456)
    //   wpf f16 [1024,1024]                 @ 6291456    (2,097,152)
    //   xf  f16 [4096,1024] | yb f16 reuse  @ 8388608    (8,388,608)
    //   qf  f16 [32][2048][64]              @ 16777216   (8,388,608)
    //   kf  f16 [32][2048][64]              @ 25165824   (8,388,608)
    //   vb  f16 [32][2048][64]              @ 33554432   (8,388,608)
    //   vt  f16 [32][64][2048]              @ 41943040   (8,388,608)
    //   py  f16 [2560][64][64]              @ 50331648   (20,971,520)
    //   pml f32 [2560][128]                 @ 71303168   ( 1,310,720)
    char* ws = (char*)d_ws;
    ushort_t* wqf = (ushort_t*)(ws);
    ushort_t* wpf = (ushort_t*)(ws + 6291456);
    ushort_t* xf  = (ushort_t*)(ws + 8388608);
    ushort_t* qf  = (ushort_t*)(ws + 16777216);
    ushort_t* kf  = (ushort_t*)(ws + 25165824);
    ushort_t* vb  = (ushort_t*)(ws + 33554432);
    ushort_t* vt  = (ushort_t*)(ws + 41943040);
    ushort_t* py  = (ushort_t*)(ws + 50331648);
    float*    pml = (float*)   (ws + 71303168);
    ushort_t* yb  = xf;   // reused after qkv GEMM consumed xf

    const dim3 blk(256);

    // one fused convert launch: x, w_qkv, w_proj -> f16
    conv3_f32_f16<<<dim3(2048), blk, 0, stream>>>(
        x, xf, M_TOTAL * DMODEL / 4,
        w_qkv, wqf, 3 * DMODEL * DMODEL / 4,
        w_proj, wpf, DMODEL * DMODEL / 4);

    // qkv = x @ w_qkv^T, single fp16 GEMM (N=3072), epilogue scatters q/k/v
    gemm_f16_nt<128, true><<<dim3(3 * DMODEL / 128, M_TOTAL / 128), blk, 0, stream>>>(
        xf, wqf, nullptr, nullptr, qf, kf, vb, M_TOTAL, 3 * DMODEL, DMODEL);

    transpose_v<<<dim3(CTXLEN / 64, BATCH * NHEAD), blk, 0, stream>>>(vb, vt);

    // split-KV attention units (LPT order) + merge
    attn_fwd7<<<dim3(2560), blk, 0, stream>>>(qf, kf, vt, py, pml);
    merge_attn<<<dim3(1024), blk, 0, stream>>>(py, pml, yb);

    // out = y @ w_proj^T + b  — BN=64 tiles -> 512 blocks (2/CU)
    gemm_f16_nt<64, false><<<dim3(DMODEL / 64, M_TOTAL / 128), blk, 0, stream>>>(
        yb, wpf, b_proj, out, nullptr, nullptr, nullptr, M_TOTAL, DMODEL, DMODEL);
}